// Round 2
// baseline (4064.462 us; speedup 1.0000x reference)
//
#include <hip/hip_runtime.h>
#include <hip/hip_bf16.h>

#define KNN_K 20
typedef _Float16 f16;

__device__ __forceinline__ float lrelu(float x){ return x >= 0.f ? x : 0.2f*x; }

// order-preserving float->u32 map, packed with ~index so that
// (value desc, index asc) == key desc, and keys are unique.
__device__ __forceinline__ unsigned long long pack_key(float v, int m){
  unsigned u = __float_as_uint(v);
  unsigned s = (u & 0x80000000u) ? ~u : (u | 0x80000000u);
  return ((unsigned long long)s << 32) | (unsigned)(~m);
}

__device__ __forceinline__ void topk_insert_u64(unsigned long long* tk, unsigned long long key){
  if (key > tk[KNN_K-1]){
    #pragma unroll
    for (int j = KNN_K-1; j >= 1; --j){
      unsigned long long pv = tk[j-1];
      bool keep = tk[j] > key;   // entries > key keep their slot
      bool ins  = pv   > key;    // prev > key -> this slot receives key
      tk[j] = keep ? tk[j] : (ins ? key : pv);
    }
    if (tk[0] < key) tk[0] = key;
  }
}

// ---------------- build x0 = [pos(3); onehot(9)] ----------------
__global__ __launch_bounds__(256) void build_x0(
    const float* __restrict__ pos, const int* __restrict__ nt,
    float* __restrict__ x0NC, float* __restrict__ x0hf, f16* __restrict__ xx0, int N)
{
  int n = blockIdx.x*256 + threadIdx.x;
  if (n >= N) return;
  float v[12];
  v[0]=pos[n*3+0]; v[1]=pos[n*3+1]; v[2]=pos[n*3+2];
  int t = nt[n];
  #pragma unroll
  for (int c=0;c<9;++c) v[3+c] = (t==c) ? 1.f : 0.f;
  // jnp.sum(xh*xh): squares rounded to f16 elementwise, then f32-accumulated
  // (jax upcast_f16_for_computation), single rounding to f16 at the end.
  float xa = 0.f;
  #pragma unroll
  for (int c=0;c<12;++c){
    x0NC[(size_t)n*12+c] = v[c];
    f16 h = (f16)v[c];
    float hf = (float)h;
    x0hf[(size_t)n*12+c] = hf;
    f16 pe = (f16)(hf*hf);       // elementwise xh*xh rounds to f16
    xa += (float)pe;             // f32 accumulation
  }
  xx0[n] = (f16)xa;
}

// ---------------- weight transpose: dst[c*O+o] = src[o*stride+coff+c] ----------------
__global__ __launch_bounds__(256) void transpose_w(
    const float* __restrict__ src, float* __restrict__ dst, int O, int C, int stride, int coff)
{
  int i = blockIdx.x*256 + threadIdx.x;
  if (i >= O*C) return;
  int o = i / C, c = i % C;
  dst[(size_t)c*O + o] = src[(size_t)o*stride + coff + c];
}

// ---------------- kNN partial: each (64-point block, m-slice) -> top-20 keys ----------------
template<int C>
__global__ __launch_bounds__(64) void knn_partial(
    const float* __restrict__ xhf, const f16* __restrict__ xx,
    unsigned long long* __restrict__ pl, int N, int MS)
{
  int lane = threadIdx.x;
  int n = blockIdx.x*64 + lane;
  int ms = blockIdx.y;
  int m0 = (int)(((long long)N * ms) / MS);
  int m1 = (int)(((long long)N * (ms+1)) / MS);
  int nn = n < N ? n : N-1;
  float q[C];
  #pragma unroll
  for (int c=0;c<C;++c) q[c] = xhf[(size_t)nn*C + c];
  f16 qxx = xx[nn];
  unsigned long long tk[KNN_K];
  #pragma unroll
  for (int j=0;j<KNN_K;++j) tk[j] = 0ull;   // any real key > 0

  for (int m = m0; m < m1; ++m){
    const float* __restrict__ row = xhf + (size_t)m*C;
    float dot = 0.f;
    #pragma unroll
    for (int c=0;c<C;++c) dot = fmaf(q[c], row[c], dot);  // f32 accum of exact f16 products
    f16 ih = (f16)dot;                  // matmul output rounds to f16
    f16 mi = ih * (f16)(-2.0f);         // inner = -2*einsum (exact scale)
    f16 t1 = (-xx[m]) - mi;             // (-xx[m] - inner)
    f16 pdh = t1 - qxx;                 // ... - xx[n]
    float v = (float)pdh;
    topk_insert_u64(tk, pack_key(v, m));
  }
  if (n < N){
    unsigned long long* dst = pl + ((size_t)n*MS + ms)*KNN_K;
    #pragma unroll
    for (int j=0;j<KNN_K;++j) dst[j] = tk[j];
  }
}

__global__ __launch_bounds__(256) void knn_merge(
    const unsigned long long* __restrict__ pl, int* __restrict__ idx, int N, int MS)
{
  int n = blockIdx.x*256 + threadIdx.x;
  if (n >= N) return;
  unsigned long long tk[KNN_K];
  #pragma unroll
  for (int j=0;j<KNN_K;++j) tk[j] = 0ull;
  const unsigned long long* src = pl + (size_t)n*MS*KNN_K;
  int tot = MS*KNN_K;
  for (int i=0;i<tot;++i) topk_insert_u64(tk, src[i]);
  #pragma unroll
  for (int j=0;j<KNN_K;++j) idx[(size_t)n*KNN_K + j] = (int)(~(unsigned)(tk[j] & 0xffffffffu));
}

// ---------------- fused edge-conv (partial over k-slices) ----------------
// f1 = lrelu(bnA(WA^T . [nb-c; c])); if SECOND: f2 = lrelu(bnB(WB . f1)); max-pool into pmax slice
template<int CIN, bool SECOND>
__global__ __launch_bounds__(128) void edgeconv_partial(
    const float* __restrict__ xNC, const int* __restrict__ idx,
    const float* __restrict__ WAT,   // [2*CIN][64]
    const float* __restrict__ bnA,   // 4 x 64 (g,b,m,v)
    const float* __restrict__ WB,    // [64][64] row-major or null
    const float* __restrict__ bnB,
    float* __restrict__ pmax,        // [KS][N*64]
    int N, int kPerSlice)
{
  __shared__ float c0s[128][CIN+1];
  __shared__ float msA[64], tsA[64], bsA[64];
  __shared__ float msB[64], tsB[64], bsB[64];
  int tid = threadIdx.x;
  int n = blockIdx.x*128 + tid;
  int ks = blockIdx.y;
  if (tid < 64){
    tsA[tid] = bnA[tid] / sqrtf(bnA[192+tid] + 1e-5f);
    bsA[tid] = bnA[64+tid];
    msA[tid] = bnA[128+tid];
    if (SECOND){
      tsB[tid] = bnB[tid] / sqrtf(bnB[192+tid] + 1e-5f);
      bsB[tid] = bnB[64+tid];
      msB[tid] = bnB[128+tid];
    }
  }
  int nn = n < N ? n : N-1;
  #pragma unroll
  for (int c=0;c<CIN;++c) c0s[tid][c] = xNC[(size_t)nn*CIN + c];
  __syncthreads();

  float acc[64];
  #pragma unroll
  for (int o=0;o<64;++o) acc[o] = -INFINITY;

  for (int kk=0; kk<kPerSlice; ++kk){
    int k = ks*kPerSlice + kk;
    int j = idx[(size_t)nn*KNN_K + k];
    float f1[64];
    #pragma unroll
    for (int o=0;o<64;++o) f1[o] = 0.f;
    // diff segment: c in [0, CIN)
    #pragma unroll 4
    for (int c=0;c<CIN;++c){
      float xv = xNC[(size_t)j*CIN + c] - c0s[tid][c];
      const float* wr = WAT + (size_t)c*64;
      #pragma unroll
      for (int o=0;o<64;++o) f1[o] = fmaf(wr[o], xv, f1[o]);
    }
    // center segment: c in [CIN, 2*CIN)
    #pragma unroll 4
    for (int c=0;c<CIN;++c){
      float xv = c0s[tid][c];
      const float* wr = WAT + (size_t)(CIN+c)*64;
      #pragma unroll
      for (int o=0;o<64;++o) f1[o] = fmaf(wr[o], xv, f1[o]);
    }
    #pragma unroll
    for (int o=0;o<64;++o) f1[o] = lrelu(fmaf(f1[o]-msA[o], tsA[o], bsA[o]));
    if (SECOND){
      #pragma unroll
      for (int o2=0;o2<64;++o2){
        const float* wr = WB + (size_t)o2*64;
        float a = 0.f;
        #pragma unroll
        for (int c=0;c<64;++c) a = fmaf(wr[c], f1[c], a);
        a = lrelu(fmaf(a-msB[o2], tsB[o2], bsB[o2]));
        acc[o2] = fmaxf(acc[o2], a);
      }
    } else {
      #pragma unroll
      for (int o=0;o<64;++o) acc[o] = fmaxf(acc[o], f1[o]);
    }
  }
  if (n < N){
    float* dst = pmax + ((size_t)ks*N + n)*64;
    #pragma unroll
    for (int o=0;o<64;++o) dst[o] = acc[o];
  }
}

// ---------------- finalize: max over slices, emit NC/CN (+f16 image & xx) ----------------
template<bool AUX>
__global__ __launch_bounds__(256) void ec_finalize(
    const float* __restrict__ pmax, int KS,
    float* __restrict__ outNC, float* __restrict__ outCN,
    float* __restrict__ outhf, f16* __restrict__ outxx, int N)
{
  int n = blockIdx.x*256 + threadIdx.x;
  if (n >= N) return;
  float xa = 0.f;
  #pragma unroll 4
  for (int o=0;o<64;++o){
    float v = -INFINITY;
    for (int s=0;s<KS;++s) v = fmaxf(v, pmax[((size_t)s*N + n)*64 + o]);
    if (outNC) outNC[(size_t)n*64 + o] = v;
    outCN[(size_t)o*N + n] = v;
    if (AUX){
      f16 h = (f16)v;
      float hf = (float)h;
      outhf[(size_t)n*64 + o] = hf;
      f16 pe = (f16)(hf*hf);   // elementwise square rounded to f16
      xa += (float)pe;         // f32 accumulation (jax upcast semantics)
    }
  }
  if (AUX) outxx[n] = (f16)xa;
}

// ---------------- fused 1x1-conv over concat inputs (+bn+lrelu), opt. global max ----------------
template<bool DOMAX>
__global__ __launch_bounds__(256) void conv_fused(
    const float* __restrict__ WT, int O,
    const float* __restrict__ sA, int cAn,
    const float* __restrict__ sB, int cBn,
    const float* __restrict__ sC, int cCn,
    const float* __restrict__ bnp,
    const float* __restrict__ extra,
    float* __restrict__ out, int N)
{
  __shared__ float red[4][64];
  int tid = threadIdx.x;
  int n = blockIdx.x*256 + tid;
  int ob = blockIdx.y*64;
  float acc[64];
  #pragma unroll
  for (int o=0;o<64;++o) acc[o] = 0.f;
  int cbase = 0;
  if (sA){
    for (int c=0;c<cAn;++c){
      float xv = sA[(size_t)c*N + n];
      const float* wr = WT + (size_t)(cbase+c)*O + ob;
      #pragma unroll
      for (int o=0;o<64;++o) acc[o] = fmaf(wr[o], xv, acc[o]);
    }
    cbase += cAn;
  }
  if (sB){
    for (int c=0;c<cBn;++c){
      float xv = sB[(size_t)c*N + n];
      const float* wr = WT + (size_t)(cbase+c)*O + ob;
      #pragma unroll
      for (int o=0;o<64;++o) acc[o] = fmaf(wr[o], xv, acc[o]);
    }
    cbase += cBn;
  }
  if (sC){
    for (int c=0;c<cCn;++c){
      float xv = sC[(size_t)c*N + n];
      const float* wr = WT + (size_t)(cbase+c)*O + ob;
      #pragma unroll
      for (int o=0;o<64;++o) acc[o] = fmaf(wr[o], xv, acc[o]);
    }
  }
  #pragma unroll
  for (int o=0;o<64;++o){
    int og = ob + o;
    float a = acc[o];
    if (extra) a += extra[og];
    float t = bnp[og] / sqrtf(bnp[3*O+og] + 1e-5f);
    a = fmaf(a - bnp[2*O+og], t, bnp[1*O+og]);
    acc[o] = lrelu(a);
  }
  if (!DOMAX){
    #pragma unroll
    for (int o=0;o<64;++o) out[(size_t)(ob+o)*N + n] = acc[o];
  } else {
    int lane = tid & 63, wv = tid >> 6;
    #pragma unroll
    for (int o=0;o<64;++o){
      float v = acc[o];
      #pragma unroll
      for (int s=32;s>=1;s>>=1) v = fmaxf(v, __shfl_xor(v, s, 64));
      if (lane == 0) red[wv][o] = v;
    }
    __syncthreads();
    if (tid < 64){
      float m0 = fmaxf(red[0][tid], red[1][tid]);
      float m1 = fmaxf(red[2][tid], red[3][tid]);
      out[(size_t)(ob+tid)*gridDim.x + blockIdx.x] = fmaxf(m0, m1);
    }
  }
}

__global__ __launch_bounds__(256) void gmax_final(
    const float* __restrict__ gpart, float* __restrict__ g, int O, int P)
{
  int o = blockIdx.x*256 + threadIdx.x;
  if (o >= O) return;
  float m = -INFINITY;
  for (int p=0;p<P;++p) m = fmaxf(m, gpart[(size_t)o*P + p]);
  g[o] = m;
}

__global__ __launch_bounds__(256) void bias7_kernel(
    const float* __restrict__ W7, const float* __restrict__ g, float* __restrict__ b7)
{
  int o = blockIdx.x*256 + threadIdx.x;
  if (o >= 512) return;
  float a = 0.f;
  for (int c=0;c<1024;++c) a = fmaf(W7[(size_t)o*1216 + c], g[c], a);
  b7[o] = a;
}

__global__ __launch_bounds__(256) void w9_kernel(
    const float* __restrict__ W9, const float* __restrict__ h8, float* __restrict__ out, int N)
{
  int n = blockIdx.x*256 + threadIdx.x;
  if (n >= N) return;
  float a0=0.f, a1=0.f, a2=0.f;
  for (int c=0;c<256;++c){
    float xv = h8[(size_t)c*N + n];
    a0 = fmaf(W9[c],       xv, a0);
    a1 = fmaf(W9[256+c],   xv, a1);
    a2 = fmaf(W9[512+c],   xv, a2);
  }
  out[(size_t)n*3+0]=a0; out[(size_t)n*3+1]=a1; out[(size_t)n*3+2]=a2;
}

extern "C" void kernel_launch(void* const* d_in, const int* in_sizes, int n_in,
                              void* d_out, int out_size, void* d_ws, size_t ws_size,
                              hipStream_t stream) {
  const float* curr_pos = (const float*)d_in[0];
  const int*   node_t   = (const int*)  d_in[1];
  const float* W1 = (const float*)d_in[2];
  const float* W2 = (const float*)d_in[3];
  const float* W3 = (const float*)d_in[4];
  const float* W4 = (const float*)d_in[5];
  const float* W5 = (const float*)d_in[6];
  const float* W6 = (const float*)d_in[7];
  const float* W7 = (const float*)d_in[8];
  const float* W8 = (const float*)d_in[9];
  const float* W9 = (const float*)d_in[10];
  const float* bn1 = (const float*)d_in[11];
  const float* bn2 = (const float*)d_in[12];
  const float* bn3 = (const float*)d_in[13];
  const float* bn4 = (const float*)d_in[14];
  const float* bn5 = (const float*)d_in[15];
  const float* bn6 = (const float*)d_in[16];
  const float* bn7 = (const float*)d_in[17];
  const float* bn8 = (const float*)d_in[18];
  float* out = (float*)d_out;

  const int N = in_sizes[0] / 3;
  const int MS = 16;               // kNN m-slices
  const int KS = 5;                // edgeconv k-slices (4 edges each)
  const int NB = (N + 255) / 256;  // n-blocks for conv kernels

  char* ws = (char*)d_ws;
  size_t off = 0;
  auto A = [&](size_t b){ size_t o = off; off = (o + b + 255) & ~(size_t)255; return o; };

  float* x0NC = (float*)(ws + A((size_t)N*12*4));
  float* x0hf = (float*)(ws + A((size_t)N*12*4));
  f16*   xx0  = (f16*)  (ws + A((size_t)N*2));
  float* x1NC = (float*)(ws + A((size_t)N*64*4));
  float* x1CN = (float*)(ws + A((size_t)N*64*4));
  float* x1hf = (float*)(ws + A((size_t)N*64*4));
  f16*   xx1  = (f16*)  (ws + A((size_t)N*2));
  float* x2NC = (float*)(ws + A((size_t)N*64*4));
  float* x2CN = (float*)(ws + A((size_t)N*64*4));
  float* x2hf = (float*)(ws + A((size_t)N*64*4));
  f16*   xx2  = (f16*)  (ws + A((size_t)N*2));
  float* x3CN = (float*)(ws + A((size_t)N*64*4));
  int* idx1 = (int*)(ws + A((size_t)N*KNN_K*4));
  int* idx2 = (int*)(ws + A((size_t)N*KNN_K*4));
  int* idx3 = (int*)(ws + A((size_t)N*KNN_K*4));
  float* w1t  = (float*)(ws + A((size_t)24*64*4));
  float* w3t  = (float*)(ws + A((size_t)128*64*4));
  float* w5t  = (float*)(ws + A((size_t)128*64*4));
  float* w6t  = (float*)(ws + A((size_t)192*1024*4));
  float* w7xt = (float*)(ws + A((size_t)192*512*4));
  float* w8t  = (float*)(ws + A((size_t)512*256*4));
  float* gpart= (float*)(ws + A((size_t)1024*NB*4));
  float* gbuf = (float*)(ws + A((size_t)1024*4));
  float* b7   = (float*)(ws + A((size_t)512*4));

  size_t plB   = (size_t)N*MS*KNN_K*8;
  size_t pmB   = (size_t)KS*N*64*4;
  size_t h7B   = (size_t)512*N*4;
  size_t h8B   = (size_t)256*N*4;
  size_t h78B  = ((h7B + 255) & ~(size_t)255) + h8B;
  size_t uniB  = plB > pmB ? plB : pmB;
  if (h78B > uniB) uniB = h78B;
  size_t uniOff = A(uniB);
  unsigned long long* pl = (unsigned long long*)(ws + uniOff);
  float* pmax = (float*)(ws + uniOff);
  float* h7   = (float*)(ws + uniOff);
  float* h8   = (float*)(ws + uniOff + ((h7B + 255) & ~(size_t)255));
  if (off > ws_size) return;  // workspace too small -> fail loudly via absmax

  dim3 b256(256);
  // stage 0: inputs
  build_x0<<<dim3((N+255)/256), b256, 0, stream>>>(curr_pos, node_t, x0NC, x0hf, xx0, N);
  // weight transposes
  transpose_w<<<dim3((64*24+255)/256),  b256, 0, stream>>>(W1, w1t, 64, 24, 24, 0);
  transpose_w<<<dim3((64*128+255)/256), b256, 0, stream>>>(W3, w3t, 64, 128, 128, 0);
  transpose_w<<<dim3((64*128+255)/256), b256, 0, stream>>>(W5, w5t, 64, 128, 128, 0);
  transpose_w<<<dim3((1024*192+255)/256), b256, 0, stream>>>(W6, w6t, 1024, 192, 192, 0);
  transpose_w<<<dim3((512*192+255)/256),  b256, 0, stream>>>(W7, w7xt, 512, 192, 1216, 1024);
  transpose_w<<<dim3((256*512+255)/256),  b256, 0, stream>>>(W8, w8t, 256, 512, 512, 0);

  dim3 gknn((N+63)/64, MS), b64(64);
  dim3 gec((N+127)/128, KS), b128(128);
  dim3 gfin((N+255)/256);

  // round 1
  knn_partial<12><<<gknn, b64, 0, stream>>>(x0hf, xx0, pl, N, MS);
  knn_merge<<<gfin, b256, 0, stream>>>(pl, idx1, N, MS);
  edgeconv_partial<12,true><<<gec, b128, 0, stream>>>(x0NC, idx1, w1t, bn1, W2, bn2, pmax, N, 4);
  ec_finalize<true><<<gfin, b256, 0, stream>>>(pmax, KS, x1NC, x1CN, x1hf, xx1, N);
  // round 2
  knn_partial<64><<<gknn, b64, 0, stream>>>(x1hf, xx1, pl, N, MS);
  knn_merge<<<gfin, b256, 0, stream>>>(pl, idx2, N, MS);
  edgeconv_partial<64,true><<<gec, b128, 0, stream>>>(x1NC, idx2, w3t, bn3, W4, bn4, pmax, N, 4);
  ec_finalize<true><<<gfin, b256, 0, stream>>>(pmax, KS, x2NC, x2CN, x2hf, xx2, N);
  // round 3
  knn_partial<64><<<gknn, b64, 0, stream>>>(x2hf, xx2, pl, N, MS);
  knn_merge<<<gfin, b256, 0, stream>>>(pl, idx3, N, MS);
  edgeconv_partial<64,false><<<gec, b128, 0, stream>>>(x2NC, idx3, w5t, bn5, nullptr, nullptr, pmax, N, 4);
  ec_finalize<false><<<gfin, b256, 0, stream>>>(pmax, KS, nullptr, x3CN, nullptr, nullptr, N);
  // head
  conv_fused<true><<<dim3(NB, 16), b256, 0, stream>>>(w6t, 1024, x1CN, 64, x2CN, 64, x3CN, 64, bn6, nullptr, gpart, N);
  gmax_final<<<dim3(4), b256, 0, stream>>>(gpart, gbuf, 1024, NB);
  bias7_kernel<<<dim3(2), b256, 0, stream>>>(W7, gbuf, b7);
  conv_fused<false><<<dim3(NB, 8), b256, 0, stream>>>(w7xt, 512, x1CN, 64, x2CN, 64, x3CN, 64, bn7, b7, h7, N);
  conv_fused<false><<<dim3(NB, 4), b256, 0, stream>>>(w8t, 256, h7, 512, nullptr, 0, nullptr, 0, bn8, nullptr, h8, N);
  w9_kernel<<<gfin, b256, 0, stream>>>(W9, h8, out, N);
}

// Round 3
// 3433.605 us; speedup vs baseline: 1.1837x; 1.1837x over previous
//
#include <hip/hip_runtime.h>
#include <hip/hip_bf16.h>

#define KNN_K 20
typedef _Float16 f16;
typedef _Float16 half8 __attribute__((ext_vector_type(8)));
typedef float f32x4 __attribute__((ext_vector_type(4)));

__device__ __forceinline__ float lrelu(float x){ return x >= 0.f ? x : 0.2f*x; }

__device__ __forceinline__ f16 us2h(unsigned short u){ union{unsigned short u; f16 h;} x; x.u=u; return x.h; }
__device__ __forceinline__ unsigned short h2us(f16 h){ union{unsigned short u; f16 h;} x; x.h=h; return x.u; }

// order-preserving float->u32 map, packed with ~index so that
// (value desc, index asc) == key desc, and keys are unique.
__device__ __forceinline__ unsigned long long pack_key(float v, int m){
  unsigned u = __float_as_uint(v);
  unsigned s = (u & 0x80000000u) ? ~u : (u | 0x80000000u);
  return ((unsigned long long)s << 32) | (unsigned)(~m);
}

__device__ __forceinline__ void topk_insert_u64(unsigned long long* tk, unsigned long long key){
  if (key > tk[KNN_K-1]){
    #pragma unroll
    for (int j = KNN_K-1; j >= 1; --j){
      unsigned long long pv = tk[j-1];
      bool keep = tk[j] > key;
      bool ins  = pv   > key;
      tk[j] = keep ? tk[j] : (ins ? key : pv);
    }
    if (tk[0] < key) tk[0] = key;
  }
}

// ---------------- build x0 = [pos(3); onehot(9)] ----------------
// writes f32 NC image, f16 (zero-padded to 32) image, and xx (f16 bits)
__global__ __launch_bounds__(256) void build_x0(
    const float* __restrict__ pos, const int* __restrict__ nt,
    float* __restrict__ x0NC, unsigned short* __restrict__ xh0,
    unsigned short* __restrict__ xx0, int N)
{
  int n = blockIdx.x*256 + threadIdx.x;
  if (n >= N) return;
  float v[12];
  v[0]=pos[n*3+0]; v[1]=pos[n*3+1]; v[2]=pos[n*3+2];
  int t = nt[n];
  #pragma unroll
  for (int c=0;c<9;++c) v[3+c] = (t==c) ? 1.f : 0.f;
  float xa = 0.f;
  #pragma unroll
  for (int c=0;c<12;++c){
    x0NC[(size_t)n*12+c] = v[c];
    f16 h = (f16)v[c];
    float hf = (float)h;
    xh0[(size_t)n*32+c] = h2us(h);
    f16 pe = (f16)(hf*hf);       // elementwise xh*xh rounds to f16
    xa += (float)pe;             // f32 accumulation (jax upcast semantics)
  }
  #pragma unroll
  for (int c=12;c<32;++c) xh0[(size_t)n*32+c] = 0;   // zero pad: dot unchanged
  xx0[n] = h2us((f16)xa);
}

// ---------------- weight transpose: dst[c*O+o] = src[o*stride+coff+c] ----------------
__global__ __launch_bounds__(256) void transpose_w(
    const float* __restrict__ src, float* __restrict__ dst, int O, int C, int stride, int coff)
{
  int i = blockIdx.x*256 + threadIdx.x;
  if (i >= O*C) return;
  int o = i / C, c = i % C;
  dst[(size_t)c*O + o] = src[(size_t)o*stride + coff + c];
}

// ---------------- fused MFMA kNN ----------------
// Block: 256 thr (4 waves) owns 16 queries. D = cand(m rows) x query(n cols) via
// mfma_f32_16x16x32_f16 (exact f16 products, f32 accum — matches jnp einsum
// up to f32 summation order). Per-lane register top-20, two-stage LDS merge.
template<int C>
__global__ __launch_bounds__(256) void knn_mfma(
    const unsigned short* __restrict__ xh,  // [N][C] f16 bits
    const unsigned short* __restrict__ xx,  // [N]   f16 bits
    int* __restrict__ idx, int N)
{
  __shared__ unsigned short xxs[8192];
  __shared__ unsigned long long lists[16][16][KNN_K];  // [n][wave*4+g][k]
  __shared__ unsigned long long part[16][4][KNN_K];
  int tid = threadIdx.x;
  int w = tid >> 6, lane = tid & 63;
  int g = lane >> 4, c = lane & 15;
  int n0 = blockIdx.x * 16;

  // stage xx (N*2 bytes, 8B chunks)
  for (int i = tid; i < N/4; i += 256)
    ((unsigned long long*)xxs)[i] = ((const unsigned long long*)xx)[i];
  __syncthreads();

  // query (B) fragments: B[k][col]: col=lane&15 -> n, k=(lane>>4)*8..+7
  half8 bfrag[C/32];
  #pragma unroll
  for (int kc=0; kc<C/32; ++kc)
    bfrag[kc] = *reinterpret_cast<const half8*>(xh + (size_t)(n0 + c)*C + kc*32 + g*8);
  f16 qxx = us2h(xxs[n0 + c]);

  unsigned long long tk[KNN_K];
  #pragma unroll
  for (int j=0;j<KNN_K;++j) tk[j] = 0ull;

  int ntiles = N >> 6;             // m-tiles of 64
  for (int t = w; t < ntiles; t += 4){
    int mbase = t << 6;
    #pragma unroll
    for (int ms=0; ms<4; ++ms){
      int mrow = mbase + ms*16;
      f32x4 acc = {0.f,0.f,0.f,0.f};
      #pragma unroll
      for (int kc=0; kc<C/32; ++kc){
        half8 af = *reinterpret_cast<const half8*>(xh + (size_t)(mrow + c)*C + kc*32 + g*8);
        acc = __builtin_amdgcn_mfma_f32_16x16x32_f16(af, bfrag[kc], acc, 0, 0, 0);
      }
      #pragma unroll
      for (int j=0;j<4;++j){
        int m = mrow + g*4 + j;
        f16 dh = (f16)acc[j];          // einsum output rounds to f16
        f16 mi = dh * (f16)(-2.0f);    // inner = -2*dot (exact scale)
        f16 xm = us2h(xxs[m]);
        f16 t1 = (-xm) - mi;           // (-xx[m] - inner)
        f16 pdh = t1 - qxx;            // ... - xx[n]
        topk_insert_u64(tk, pack_key((float)pdh, m));
      }
    }
  }

  {
    unsigned long long* dst = lists[c][w*4 + g];
    #pragma unroll
    for (int j=0;j<KNN_K;++j) dst[j] = tk[j];
  }
  __syncthreads();

  if (tid < 64){
    int n = tid & 15, q = tid >> 4;
    unsigned long long tk2[KNN_K];
    #pragma unroll
    for (int j=0;j<KNN_K;++j) tk2[j] = 0ull;
    for (int li=0; li<4; ++li){
      const unsigned long long* src = lists[n][q*4 + li];
      for (int j=0;j<KNN_K;++j) topk_insert_u64(tk2, src[j]);
    }
    unsigned long long* dst = part[n][q];
    #pragma unroll
    for (int j=0;j<KNN_K;++j) dst[j] = tk2[j];
  }
  __syncthreads();

  if (tid < 16){
    int n = tid;
    unsigned long long tk2[KNN_K];
    #pragma unroll
    for (int j=0;j<KNN_K;++j) tk2[j] = 0ull;
    for (int q=0; q<4; ++q){
      const unsigned long long* src = part[n][q];
      for (int j=0;j<KNN_K;++j) topk_insert_u64(tk2, src[j]);
    }
    #pragma unroll
    for (int j=0;j<KNN_K;++j)
      idx[(size_t)(n0 + n)*KNN_K + j] = (int)(~(unsigned)(tk2[j] & 0xffffffffu));
  }
}

// ---------------- fused edge-conv (partial over k-slices) ----------------
template<int CIN, bool SECOND>
__global__ __launch_bounds__(128) void edgeconv_partial(
    const float* __restrict__ xNC, const int* __restrict__ idx,
    const float* __restrict__ WAT,   // [2*CIN][64]
    const float* __restrict__ bnA,   // 4 x 64 (g,b,m,v)
    const float* __restrict__ WB,    // [64][64] row-major or null
    const float* __restrict__ bnB,
    float* __restrict__ pmax,        // [KS][N*64]
    int N, int kPerSlice)
{
  __shared__ float c0s[128][CIN+1];
  __shared__ float msA[64], tsA[64], bsA[64];
  __shared__ float msB[64], tsB[64], bsB[64];
  int tid = threadIdx.x;
  int n = blockIdx.x*128 + tid;
  int ks = blockIdx.y;
  if (tid < 64){
    tsA[tid] = bnA[tid] / sqrtf(bnA[192+tid] + 1e-5f);
    bsA[tid] = bnA[64+tid];
    msA[tid] = bnA[128+tid];
    if (SECOND){
      tsB[tid] = bnB[tid] / sqrtf(bnB[192+tid] + 1e-5f);
      bsB[tid] = bnB[64+tid];
      msB[tid] = bnB[128+tid];
    }
  }
  int nn = n < N ? n : N-1;
  #pragma unroll
  for (int c=0;c<CIN;++c) c0s[tid][c] = xNC[(size_t)nn*CIN + c];
  __syncthreads();

  float acc[64];
  #pragma unroll
  for (int o=0;o<64;++o) acc[o] = -INFINITY;

  for (int kk=0; kk<kPerSlice; ++kk){
    int k = ks*kPerSlice + kk;
    int j = idx[(size_t)nn*KNN_K + k];
    float f1[64];
    #pragma unroll
    for (int o=0;o<64;++o) f1[o] = 0.f;
    #pragma unroll 4
    for (int c=0;c<CIN;++c){
      float xv = xNC[(size_t)j*CIN + c] - c0s[tid][c];
      const float* wr = WAT + (size_t)c*64;
      #pragma unroll
      for (int o=0;o<64;++o) f1[o] = fmaf(wr[o], xv, f1[o]);
    }
    #pragma unroll 4
    for (int c=0;c<CIN;++c){
      float xv = c0s[tid][c];
      const float* wr = WAT + (size_t)(CIN+c)*64;
      #pragma unroll
      for (int o=0;o<64;++o) f1[o] = fmaf(wr[o], xv, f1[o]);
    }
    #pragma unroll
    for (int o=0;o<64;++o) f1[o] = lrelu(fmaf(f1[o]-msA[o], tsA[o], bsA[o]));
    if (SECOND){
      #pragma unroll
      for (int o2=0;o2<64;++o2){
        const float* wr = WB + (size_t)o2*64;
        float a = 0.f;
        #pragma unroll
        for (int c=0;c<64;++c) a = fmaf(wr[c], f1[c], a);
        a = lrelu(fmaf(a-msB[o2], tsB[o2], bsB[o2]));
        acc[o2] = fmaxf(acc[o2], a);
      }
    } else {
      #pragma unroll
      for (int o=0;o<64;++o) acc[o] = fmaxf(acc[o], f1[o]);
    }
  }
  if (n < N){
    float* dst = pmax + ((size_t)ks*N + n)*64;
    #pragma unroll
    for (int o=0;o<64;++o) dst[o] = acc[o];
  }
}

// ---------------- finalize: max over slices, emit NC/CN (+f16 image & xx) ----------------
template<bool AUX>
__global__ __launch_bounds__(256) void ec_finalize(
    const float* __restrict__ pmax, int KS,
    float* __restrict__ outNC, float* __restrict__ outCN,
    unsigned short* __restrict__ outh, unsigned short* __restrict__ outxx, int N)
{
  int n = blockIdx.x*256 + threadIdx.x;
  if (n >= N) return;
  float xa = 0.f;
  #pragma unroll 4
  for (int o=0;o<64;++o){
    float v = -INFINITY;
    for (int s=0;s<KS;++s) v = fmaxf(v, pmax[((size_t)s*N + n)*64 + o]);
    if (outNC) outNC[(size_t)n*64 + o] = v;
    outCN[(size_t)o*N + n] = v;
    if (AUX){
      f16 h = (f16)v;
      float hf = (float)h;
      outh[(size_t)n*64 + o] = h2us(h);
      f16 pe = (f16)(hf*hf);
      xa += (float)pe;
    }
  }
  if (AUX) outxx[n] = h2us((f16)xa);
}

// ---------------- fused 1x1-conv over concat inputs (+bn+lrelu), opt. global max ----------------
template<bool DOMAX>
__global__ __launch_bounds__(256) void conv_fused(
    const float* __restrict__ WT, int O,
    const float* __restrict__ sA, int cAn,
    const float* __restrict__ sB, int cBn,
    const float* __restrict__ sC, int cCn,
    const float* __restrict__ bnp,
    const float* __restrict__ extra,
    float* __restrict__ out, int N)
{
  __shared__ float red[4][64];
  int tid = threadIdx.x;
  int n = blockIdx.x*256 + tid;
  int ob = blockIdx.y*64;
  float acc[64];
  #pragma unroll
  for (int o=0;o<64;++o) acc[o] = 0.f;
  int cbase = 0;
  if (sA){
    for (int c=0;c<cAn;++c){
      float xv = sA[(size_t)c*N + n];
      const float* wr = WT + (size_t)(cbase+c)*O + ob;
      #pragma unroll
      for (int o=0;o<64;++o) acc[o] = fmaf(wr[o], xv, acc[o]);
    }
    cbase += cAn;
  }
  if (sB){
    for (int c=0;c<cBn;++c){
      float xv = sB[(size_t)c*N + n];
      const float* wr = WT + (size_t)(cbase+c)*O + ob;
      #pragma unroll
      for (int o=0;o<64;++o) acc[o] = fmaf(wr[o], xv, acc[o]);
    }
    cbase += cBn;
  }
  if (sC){
    for (int c=0;c<cCn;++c){
      float xv = sC[(size_t)c*N + n];
      const float* wr = WT + (size_t)(cbase+c)*O + ob;
      #pragma unroll
      for (int o=0;o<64;++o) acc[o] = fmaf(wr[o], xv, acc[o]);
    }
  }
  #pragma unroll
  for (int o=0;o<64;++o){
    int og = ob + o;
    float a = acc[o];
    if (extra) a += extra[og];
    float t = bnp[og] / sqrtf(bnp[3*O+og] + 1e-5f);
    a = fmaf(a - bnp[2*O+og], t, bnp[1*O+og]);
    acc[o] = lrelu(a);
  }
  if (!DOMAX){
    #pragma unroll
    for (int o=0;o<64;++o) out[(size_t)(ob+o)*N + n] = acc[o];
  } else {
    int lane = tid & 63, wv = tid >> 6;
    #pragma unroll
    for (int o=0;o<64;++o){
      float v = acc[o];
      #pragma unroll
      for (int s=32;s>=1;s>>=1) v = fmaxf(v, __shfl_xor(v, s, 64));
      if (lane == 0) red[wv][o] = v;
    }
    __syncthreads();
    if (tid < 64){
      float m0 = fmaxf(red[0][tid], red[1][tid]);
      float m1 = fmaxf(red[2][tid], red[3][tid]);
      out[(size_t)(ob+tid)*gridDim.x + blockIdx.x] = fmaxf(m0, m1);
    }
  }
}

__global__ __launch_bounds__(256) void gmax_final(
    const float* __restrict__ gpart, float* __restrict__ g, int O, int P)
{
  int o = blockIdx.x*256 + threadIdx.x;
  if (o >= O) return;
  float m = -INFINITY;
  for (int p=0;p<P;++p) m = fmaxf(m, gpart[(size_t)o*P + p]);
  g[o] = m;
}

__global__ __launch_bounds__(256) void bias7_kernel(
    const float* __restrict__ W7, const float* __restrict__ g, float* __restrict__ b7)
{
  int o = blockIdx.x*256 + threadIdx.x;
  if (o >= 512) return;
  float a = 0.f;
  for (int c=0;c<1024;++c) a = fmaf(W7[(size_t)o*1216 + c], g[c], a);
  b7[o] = a;
}

__global__ __launch_bounds__(256) void w9_kernel(
    const float* __restrict__ W9, const float* __restrict__ h8, float* __restrict__ out, int N)
{
  int n = blockIdx.x*256 + threadIdx.x;
  if (n >= N) return;
  float a0=0.f, a1=0.f, a2=0.f;
  for (int c=0;c<256;++c){
    float xv = h8[(size_t)c*N + n];
    a0 = fmaf(W9[c],       xv, a0);
    a1 = fmaf(W9[256+c],   xv, a1);
    a2 = fmaf(W9[512+c],   xv, a2);
  }
  out[(size_t)n*3+0]=a0; out[(size_t)n*3+1]=a1; out[(size_t)n*3+2]=a2;
}

extern "C" void kernel_launch(void* const* d_in, const int* in_sizes, int n_in,
                              void* d_out, int out_size, void* d_ws, size_t ws_size,
                              hipStream_t stream) {
  const float* curr_pos = (const float*)d_in[0];
  const int*   node_t   = (const int*)  d_in[1];
  const float* W1 = (const float*)d_in[2];
  const float* W2 = (const float*)d_in[3];
  const float* W3 = (const float*)d_in[4];
  const float* W4 = (const float*)d_in[5];
  const float* W5 = (const float*)d_in[6];
  const float* W6 = (const float*)d_in[7];
  const float* W7 = (const float*)d_in[8];
  const float* W8 = (const float*)d_in[9];
  const float* W9 = (const float*)d_in[10];
  const float* bn1 = (const float*)d_in[11];
  const float* bn2 = (const float*)d_in[12];
  const float* bn3 = (const float*)d_in[13];
  const float* bn4 = (const float*)d_in[14];
  const float* bn5 = (const float*)d_in[15];
  const float* bn6 = (const float*)d_in[16];
  const float* bn7 = (const float*)d_in[17];
  const float* bn8 = (const float*)d_in[18];
  float* out = (float*)d_out;

  const int N = in_sizes[0] / 3;
  const int KS = 5;                // edgeconv k-slices (4 edges each)
  const int NB = (N + 255) / 256;

  char* ws = (char*)d_ws;
  size_t off = 0;
  auto A = [&](size_t b){ size_t o = off; off = (o + b + 255) & ~(size_t)255; return o; };

  float* x0NC = (float*)(ws + A((size_t)N*12*4));
  unsigned short* xh0 = (unsigned short*)(ws + A((size_t)N*32*2));
  unsigned short* xx0 = (unsigned short*)(ws + A((size_t)N*2));
  float* x1NC = (float*)(ws + A((size_t)N*64*4));
  float* x1CN = (float*)(ws + A((size_t)N*64*4));
  unsigned short* xh1 = (unsigned short*)(ws + A((size_t)N*64*2));
  unsigned short* xx1 = (unsigned short*)(ws + A((size_t)N*2));
  float* x2NC = (float*)(ws + A((size_t)N*64*4));
  float* x2CN = (float*)(ws + A((size_t)N*64*4));
  unsigned short* xh2 = (unsigned short*)(ws + A((size_t)N*64*2));
  unsigned short* xx2 = (unsigned short*)(ws + A((size_t)N*2));
  float* x3CN = (float*)(ws + A((size_t)N*64*4));
  int* idx1 = (int*)(ws + A((size_t)N*KNN_K*4));
  int* idx2 = (int*)(ws + A((size_t)N*KNN_K*4));
  int* idx3 = (int*)(ws + A((size_t)N*KNN_K*4));
  float* w1t  = (float*)(ws + A((size_t)24*64*4));
  float* w3t  = (float*)(ws + A((size_t)128*64*4));
  float* w5t  = (float*)(ws + A((size_t)128*64*4));
  float* w6t  = (float*)(ws + A((size_t)192*1024*4));
  float* w7xt = (float*)(ws + A((size_t)192*512*4));
  float* w8t  = (float*)(ws + A((size_t)512*256*4));
  float* gpart= (float*)(ws + A((size_t)1024*NB*4));
  float* gbuf = (float*)(ws + A((size_t)1024*4));
  float* b7   = (float*)(ws + A((size_t)512*4));

  size_t pmB   = (size_t)KS*N*64*4;
  size_t h7B   = (size_t)512*N*4;
  size_t h8B   = (size_t)256*N*4;
  size_t h78B  = ((h7B + 255) & ~(size_t)255) + h8B;
  size_t uniB  = pmB > h78B ? pmB : h78B;
  size_t uniOff = A(uniB);
  float* pmax = (float*)(ws + uniOff);
  float* h7   = (float*)(ws + uniOff);
  float* h8   = (float*)(ws + uniOff + ((h7B + 255) & ~(size_t)255));
  if (off > ws_size) return;

  dim3 b256(256);
  build_x0<<<dim3((N+255)/256), b256, 0, stream>>>(curr_pos, node_t, x0NC, xh0, xx0, N);
  transpose_w<<<dim3((64*24+255)/256),  b256, 0, stream>>>(W1, w1t, 64, 24, 24, 0);
  transpose_w<<<dim3((64*128+255)/256), b256, 0, stream>>>(W3, w3t, 64, 128, 128, 0);
  transpose_w<<<dim3((64*128+255)/256), b256, 0, stream>>>(W5, w5t, 64, 128, 128, 0);
  transpose_w<<<dim3((1024*192+255)/256), b256, 0, stream>>>(W6, w6t, 1024, 192, 192, 0);
  transpose_w<<<dim3((512*192+255)/256),  b256, 0, stream>>>(W7, w7xt, 512, 192, 1216, 1024);
  transpose_w<<<dim3((256*512+255)/256),  b256, 0, stream>>>(W8, w8t, 256, 512, 512, 0);

  dim3 gknn(N/16);
  dim3 gec((N+127)/128, KS), b128(128);
  dim3 gfin((N+255)/256);

  // round 1
  knn_mfma<32><<<gknn, b256, 0, stream>>>(xh0, xx0, idx1, N);
  edgeconv_partial<12,true><<<gec, b128, 0, stream>>>(x0NC, idx1, w1t, bn1, W2, bn2, pmax, N, 4);
  ec_finalize<true><<<gfin, b256, 0, stream>>>(pmax, KS, x1NC, x1CN, xh1, xx1, N);
  // round 2
  knn_mfma<64><<<gknn, b256, 0, stream>>>(xh1, xx1, idx2, N);
  edgeconv_partial<64,true><<<gec, b128, 0, stream>>>(x1NC, idx2, w3t, bn3, W4, bn4, pmax, N, 4);
  ec_finalize<true><<<gfin, b256, 0, stream>>>(pmax, KS, x2NC, x2CN, xh2, xx2, N);
  // round 3
  knn_mfma<64><<<gknn, b256, 0, stream>>>(xh2, xx2, idx3, N);
  edgeconv_partial<64,false><<<gec, b128, 0, stream>>>(x2NC, idx3, w5t, bn5, nullptr, nullptr, pmax, N, 4);
  ec_finalize<false><<<gfin, b256, 0, stream>>>(pmax, KS, nullptr, x3CN, nullptr, nullptr, N);
  // head
  conv_fused<true><<<dim3(NB, 16), b256, 0, stream>>>(w6t, 1024, x1CN, 64, x2CN, 64, x3CN, 64, bn6, nullptr, gpart, N);
  gmax_final<<<dim3(4), b256, 0, stream>>>(gpart, gbuf, 1024, NB);
  bias7_kernel<<<dim3(2), b256, 0, stream>>>(W7, gbuf, b7);
  conv_fused<false><<<dim3(NB, 8), b256, 0, stream>>>(w7xt, 512, x1CN, 64, x2CN, 64, x3CN, 64, bn7, b7, h7, N);
  conv_fused<false><<<dim3(NB, 4), b256, 0, stream>>>(w8t, 256, h7, 512, nullptr, 0, nullptr, 0, bn8, nullptr, h8, N);
  w9_kernel<<<gfin, b256, 0, stream>>>(W9, h8, out, N);
}

// Round 4
// 1336.230 us; speedup vs baseline: 3.0417x; 2.5696x over previous
//
#include <hip/hip_runtime.h>
#include <hip/hip_bf16.h>

#define KNN_K 20
typedef _Float16 f16;
typedef _Float16 half8 __attribute__((ext_vector_type(8)));
typedef float f32x4 __attribute__((ext_vector_type(4)));

__device__ __forceinline__ float lrelu(float x){ return x >= 0.f ? x : 0.2f*x; }
__device__ __forceinline__ f16 us2h(unsigned short u){ union{unsigned short u; f16 h;} x; x.u=u; return x.h; }
__device__ __forceinline__ unsigned short h2us(f16 h){ union{unsigned short u; f16 h;} x; x.h=h; return x.u; }

// u32 key: [31:16] order-mapped f16 distance (desc), [15:0] ~m (idx asc). Unique.
__device__ __forceinline__ unsigned pack_key16(f16 v, int m){
  unsigned u = h2us(v);
  unsigned s = (u & 0x8000u) ? ((~u) & 0xFFFFu) : (u | 0x8000u);
  return (s << 16) | ((~(unsigned)m) & 0xFFFFu);
}

__device__ __forceinline__ void insert32(unsigned* tk, unsigned key){
  if (key > tk[KNN_K-1]){
    #pragma unroll
    for (int j = KNN_K-1; j >= 1; --j){
      unsigned pv = tk[j-1];
      bool keep = tk[j] > key;
      bool ins  = pv   > key;
      tk[j] = keep ? tk[j] : (ins ? key : pv);
    }
    if (tk[0] < key) tk[0] = key;
  }
}

// merge a sorted-desc 20-list into tk with early break
__device__ __forceinline__ void merge_sorted(unsigned* tk, const unsigned* src){
  #pragma unroll
  for (int j=0;j<KNN_K;++j){
    unsigned key = src[j];
    if (key <= tk[KNN_K-1]) break;
    insert32(tk, key);
  }
}

// ---------------- build x0: CN f32 + padded f16 NC + xx ----------------
__global__ __launch_bounds__(256) void build_x0(
    const float* __restrict__ pos, const int* __restrict__ nt,
    float* __restrict__ x0CN, unsigned short* __restrict__ xh0,
    unsigned short* __restrict__ xx0, int N)
{
  int n = blockIdx.x*256 + threadIdx.x;
  if (n >= N) return;
  float v[12];
  v[0]=pos[n*3+0]; v[1]=pos[n*3+1]; v[2]=pos[n*3+2];
  int t = nt[n];
  #pragma unroll
  for (int c=0;c<9;++c) v[3+c] = (t==c) ? 1.f : 0.f;
  float xa = 0.f;
  #pragma unroll
  for (int c=0;c<12;++c){
    x0CN[(size_t)c*N+n] = v[c];
    f16 h = (f16)v[c];
    float hf = (float)h;
    xh0[(size_t)n*32+c] = h2us(h);
    f16 pe = (f16)(hf*hf);       // elementwise xh*xh rounds to f16
    xa += (float)pe;             // f32 accumulation (jax upcast semantics)
  }
  #pragma unroll
  for (int c=12;c<32;++c) xh0[(size_t)n*32+c] = 0;
  xx0[n] = h2us((f16)xa);
}

// ---------------- weight transpose: dst[c*O+o] = src[o*stride+coff+c] ----------------
__global__ __launch_bounds__(256) void transpose_w(
    const float* __restrict__ src, float* __restrict__ dst, int O, int C, int stride, int coff)
{
  int i = blockIdx.x*256 + threadIdx.x;
  if (i >= O*C) return;
  int o = i / C, c = i % C;
  dst[(size_t)c*O + o] = src[(size_t)o*stride + coff + c];
}

// ---------------- fused MFMA kNN: 512 thr (8 waves) per 16 queries ----------------
template<int C>
__global__ __launch_bounds__(512) void knn_mfma(
    const unsigned short* __restrict__ xh,  // [N][C] f16 bits
    const unsigned short* __restrict__ xx,  // [N]   f16 bits
    int* __restrict__ idx, int N)
{
  __shared__ unsigned lists[16][32][KNN_K];  // 40960 B
  __shared__ unsigned part[16][8][KNN_K];    // 10240 B
  int tid = threadIdx.x;
  int w = tid >> 6, lane = tid & 63;
  int g = lane >> 4, c = lane & 15;
  int n0 = blockIdx.x * 16;

  half8 bfrag[C/32];
  #pragma unroll
  for (int kc=0; kc<C/32; ++kc)
    bfrag[kc] = *reinterpret_cast<const half8*>(xh + (size_t)(n0 + c)*C + kc*32 + g*8);
  f16 qxx = us2h(xx[n0 + c]);

  unsigned tk[KNN_K];
  #pragma unroll
  for (int j=0;j<KNN_K;++j) tk[j] = 0u;

  int ntiles = N >> 6;
  for (int t = w; t < ntiles; t += 8){
    int mbase = t << 6;
    #pragma unroll
    for (int ms=0; ms<4; ++ms){
      int mrow = mbase + ms*16;
      f32x4 acc = {0.f,0.f,0.f,0.f};
      #pragma unroll
      for (int kc=0; kc<C/32; ++kc){
        half8 af = *reinterpret_cast<const half8*>(xh + (size_t)(mrow + c)*C + kc*32 + g*8);
        acc = __builtin_amdgcn_mfma_f32_16x16x32_f16(af, bfrag[kc], acc, 0, 0, 0);
      }
      #pragma unroll
      for (int j=0;j<4;++j){
        int m = mrow + g*4 + j;
        f16 dh = (f16)acc[j];          // einsum output rounds to f16
        f16 mi = dh * (f16)(-2.0f);    // inner = -2*dot
        f16 xm = us2h(xx[m]);
        f16 t1 = (-xm) - mi;           // (-xx[m] - inner)
        f16 pdh = t1 - qxx;            // ... - xx[n]
        insert32(tk, pack_key16(pdh, m));
      }
    }
  }

  {
    unsigned* dst = lists[c][w*4 + g];
    #pragma unroll
    for (int j=0;j<KNN_K;++j) dst[j] = tk[j];
  }
  __syncthreads();

  // stage 1: 128 threads merge 4 lists -> part[n][q]
  if (tid < 128){
    int n = tid >> 3, q = tid & 7;
    unsigned tk2[KNN_K];
    #pragma unroll
    for (int j=0;j<KNN_K;++j) tk2[j] = lists[n][q*4][j];
    for (int li=1; li<4; ++li) merge_sorted(tk2, lists[n][q*4 + li]);
    unsigned* dst = part[n][q];
    #pragma unroll
    for (int j=0;j<KNN_K;++j) dst[j] = tk2[j];
  }
  __syncthreads();
  // stage 1b: 32 threads merge 4 partials -> lists[n][h]
  if (tid < 32){
    int n = tid >> 1, h = tid & 1;
    unsigned tk2[KNN_K];
    #pragma unroll
    for (int j=0;j<KNN_K;++j) tk2[j] = part[n][h*4][j];
    for (int li=1; li<4; ++li) merge_sorted(tk2, part[n][h*4 + li]);
    unsigned* dst = lists[n][h];
    #pragma unroll
    for (int j=0;j<KNN_K;++j) dst[j] = tk2[j];
  }
  __syncthreads();
  // stage 2: 16 threads merge 2 -> output (sorted: value desc, idx asc)
  if (tid < 16){
    int n = tid;
    unsigned tk2[KNN_K];
    #pragma unroll
    for (int j=0;j<KNN_K;++j) tk2[j] = lists[n][0][j];
    merge_sorted(tk2, lists[n][1]);
    #pragma unroll
    for (int j=0;j<KNN_K;++j)
      idx[(size_t)(n0 + n)*KNN_K + j] = (int)((~tk2[j]) & 0xFFFFu);
  }
}

// ---------------- per-point U/V precompute: Ut = t*(Wd X); Vtb = t*((Wc-Wd)X - m) + b ----------------
template<int CIN>
__global__ __launch_bounds__(256) void uv_kernel(
    const float* __restrict__ xCN, const float* __restrict__ W,  // [64][2*CIN]
    const float* __restrict__ bn,
    float* __restrict__ Ut, float* __restrict__ Vtb, int N)
{
  __shared__ float Ws[32][CIN];
  int tid = threadIdx.x;
  int mode = blockIdx.y;      // 0 = U (neighbor term), 1 = V (center term)
  int ob = blockIdx.z * 32;
  for (int i = tid; i < 32*CIN; i += 256){
    int oo = i / CIN, cc = i % CIN;
    float wd = W[(size_t)(ob+oo)*(2*CIN) + cc];
    float wc = W[(size_t)(ob+oo)*(2*CIN) + CIN + cc];
    Ws[oo][cc] = mode ? (wc - wd) : wd;
  }
  __syncthreads();
  int n = blockIdx.x*256 + tid;
  float x[CIN];
  #pragma unroll
  for (int c2=0;c2<CIN;++c2) x[c2] = xCN[(size_t)c2*N + n];
  float acc[32];
  #pragma unroll
  for (int oo=0;oo<32;++oo) acc[oo] = 0.f;
  #pragma unroll 4
  for (int c2=0;c2<CIN;++c2){
    float xv = x[c2];
    #pragma unroll
    for (int oo=0;oo<32;++oo) acc[oo] = fmaf(Ws[oo][c2], xv, acc[oo]);
  }
  float* dst = mode ? Vtb : Ut;
  #pragma unroll
  for (int oo=0;oo<32;++oo){
    int o = ob + oo;
    float t = bn[o] / sqrtf(bn[192+o] + 1e-5f);
    float val = mode ? fmaf(acc[oo] - bn[128+o], t, bn[64+o]) : acc[oo]*t;
    dst[(size_t)n*64 + o] = val;
  }
}

// ---------------- edge conv v2: e = lrelu(Ut[j]+Vtb[n]); opt. f2 = lrelu(bn2(W2 e)); max over k ----------------
template<bool SECOND>
__global__ __launch_bounds__(256) void edge2(
    const float* __restrict__ Ut, const float* __restrict__ Vtb,
    const int* __restrict__ idx,
    const float* __restrict__ W2, const float* __restrict__ bn2,
    float* __restrict__ outCN, unsigned short* __restrict__ outh,
    unsigned short* __restrict__ outxx, int N)
{
  int w = threadIdx.x >> 6, o = threadIdx.x & 63;
  float w2r[64]; float t2=0.f,b2=0.f,m2=0.f;
  if (SECOND){
    #pragma unroll
    for (int c2=0;c2<64;++c2) w2r[c2] = W2[(size_t)o*64 + c2];
    t2 = bn2[o]/sqrtf(bn2[192+o]+1e-5f); b2 = bn2[64+o]; m2 = bn2[128+o];
  }
  #pragma unroll 1
  for (int q=0;q<2;++q){
    int n = blockIdx.x*8 + w*2 + q;
    float vo = Vtb[(size_t)n*64 + o];
    float best = -INFINITY;
    #pragma unroll 1
    for (int k=0;k<KNN_K;++k){
      int j = idx[(size_t)n*KNN_K + k];
      float e = lrelu(Ut[(size_t)j*64 + o] + vo);
      if (SECOND){
        float s0=0.f,s1=0.f,s2=0.f,s3=0.f;
        #pragma unroll
        for (int c2=0;c2<64;c2+=4){
          s0 = fmaf(w2r[c2+0], __shfl(e, c2+0, 64), s0);
          s1 = fmaf(w2r[c2+1], __shfl(e, c2+1, 64), s1);
          s2 = fmaf(w2r[c2+2], __shfl(e, c2+2, 64), s2);
          s3 = fmaf(w2r[c2+3], __shfl(e, c2+3, 64), s3);
        }
        float s = (s0+s1)+(s2+s3);
        float f = lrelu(fmaf(s - m2, t2, b2));
        best = fmaxf(best, f);
      } else {
        best = fmaxf(best, e);
      }
    }
    outCN[(size_t)o*N + n] = best;
    if (SECOND){
      f16 h = (f16)best; float hf = (float)h;
      outh[(size_t)n*64 + o] = h2us(h);
      float pe = (float)(f16)(hf*hf);
      float ssum = pe;
      #pragma unroll
      for (int s2=32;s2>=1;s2>>=1) ssum += __shfl_xor(ssum, s2, 64);
      if (o == 0) outxx[n] = h2us((f16)ssum);
    }
  }
}

// ---------------- fused 1x1-conv over concat inputs (+bn+lrelu), opt. global max ----------------
template<bool DOMAX>
__global__ __launch_bounds__(256) void conv_fused(
    const float* __restrict__ WT, int O,
    const float* __restrict__ sA, int cAn,
    const float* __restrict__ sB, int cBn,
    const float* __restrict__ sC, int cCn,
    const float* __restrict__ bnp,
    const float* __restrict__ extra,
    float* __restrict__ out, int N)
{
  __shared__ float red[4][64];
  int tid = threadIdx.x;
  int n = blockIdx.x*256 + tid;
  int ob = blockIdx.y*64;
  float acc[64];
  #pragma unroll
  for (int o=0;o<64;++o) acc[o] = 0.f;
  int cbase = 0;
  if (sA){
    for (int c=0;c<cAn;++c){
      float xv = sA[(size_t)c*N + n];
      const float* wr = WT + (size_t)(cbase+c)*O + ob;
      #pragma unroll
      for (int o=0;o<64;++o) acc[o] = fmaf(wr[o], xv, acc[o]);
    }
    cbase += cAn;
  }
  if (sB){
    for (int c=0;c<cBn;++c){
      float xv = sB[(size_t)c*N + n];
      const float* wr = WT + (size_t)(cbase+c)*O + ob;
      #pragma unroll
      for (int o=0;o<64;++o) acc[o] = fmaf(wr[o], xv, acc[o]);
    }
    cbase += cBn;
  }
  if (sC){
    for (int c=0;c<cCn;++c){
      float xv = sC[(size_t)c*N + n];
      const float* wr = WT + (size_t)(cbase+c)*O + ob;
      #pragma unroll
      for (int o=0;o<64;++o) acc[o] = fmaf(wr[o], xv, acc[o]);
    }
  }
  #pragma unroll
  for (int o=0;o<64;++o){
    int og = ob + o;
    float a = acc[o];
    if (extra) a += extra[og];
    float t = bnp[og] / sqrtf(bnp[3*O+og] + 1e-5f);
    a = fmaf(a - bnp[2*O+og], t, bnp[1*O+og]);
    acc[o] = lrelu(a);
  }
  if (!DOMAX){
    #pragma unroll
    for (int o=0;o<64;++o) out[(size_t)(ob+o)*N + n] = acc[o];
  } else {
    int lane = tid & 63, wv = tid >> 6;
    #pragma unroll
    for (int o=0;o<64;++o){
      float v = acc[o];
      #pragma unroll
      for (int s=32;s>=1;s>>=1) v = fmaxf(v, __shfl_xor(v, s, 64));
      if (lane == 0) red[wv][o] = v;
    }
    __syncthreads();
    if (tid < 64){
      float m0 = fmaxf(red[0][tid], red[1][tid]);
      float m1 = fmaxf(red[2][tid], red[3][tid]);
      out[(size_t)(ob+tid)*gridDim.x + blockIdx.x] = fmaxf(m0, m1);
    }
  }
}

__global__ __launch_bounds__(256) void gmax_final(
    const float* __restrict__ gpart, float* __restrict__ g, int O, int P)
{
  int o = blockIdx.x*256 + threadIdx.x;
  if (o >= O) return;
  float m = -INFINITY;
  for (int p=0;p<P;++p) m = fmaxf(m, gpart[(size_t)o*P + p]);
  g[o] = m;
}

__global__ __launch_bounds__(256) void bias7_kernel(
    const float* __restrict__ W7, const float* __restrict__ g, float* __restrict__ b7)
{
  int o = blockIdx.x*256 + threadIdx.x;
  if (o >= 512) return;
  float a = 0.f;
  for (int c=0;c<1024;++c) a = fmaf(W7[(size_t)o*1216 + c], g[c], a);
  b7[o] = a;
}

__global__ __launch_bounds__(256) void w9_kernel(
    const float* __restrict__ W9, const float* __restrict__ h8, float* __restrict__ out, int N)
{
  int n = blockIdx.x*256 + threadIdx.x;
  if (n >= N) return;
  float a0=0.f, a1=0.f, a2=0.f;
  for (int c=0;c<256;++c){
    float xv = h8[(size_t)c*N + n];
    a0 = fmaf(W9[c],       xv, a0);
    a1 = fmaf(W9[256+c],   xv, a1);
    a2 = fmaf(W9[512+c],   xv, a2);
  }
  out[(size_t)n*3+0]=a0; out[(size_t)n*3+1]=a1; out[(size_t)n*3+2]=a2;
}

extern "C" void kernel_launch(void* const* d_in, const int* in_sizes, int n_in,
                              void* d_out, int out_size, void* d_ws, size_t ws_size,
                              hipStream_t stream) {
  const float* curr_pos = (const float*)d_in[0];
  const int*   node_t   = (const int*)  d_in[1];
  const float* W1 = (const float*)d_in[2];
  const float* W2 = (const float*)d_in[3];
  const float* W3 = (const float*)d_in[4];
  const float* W4 = (const float*)d_in[5];
  const float* W5 = (const float*)d_in[6];
  const float* W6 = (const float*)d_in[7];
  const float* W7 = (const float*)d_in[8];
  const float* W8 = (const float*)d_in[9];
  const float* W9 = (const float*)d_in[10];
  const float* bn1 = (const float*)d_in[11];
  const float* bn2 = (const float*)d_in[12];
  const float* bn3 = (const float*)d_in[13];
  const float* bn4 = (const float*)d_in[14];
  const float* bn5 = (const float*)d_in[15];
  const float* bn6 = (const float*)d_in[16];
  const float* bn7 = (const float*)d_in[17];
  const float* bn8 = (const float*)d_in[18];
  float* out = (float*)d_out;

  const int N = in_sizes[0] / 3;
  const int NB = (N + 255) / 256;

  char* ws = (char*)d_ws;
  size_t off = 0;
  auto A = [&](size_t b){ size_t o = off; off = (o + b + 255) & ~(size_t)255; return o; };

  float* x0CN = (float*)(ws + A((size_t)N*12*4));
  unsigned short* xh0 = (unsigned short*)(ws + A((size_t)N*32*2));
  unsigned short* xx0 = (unsigned short*)(ws + A((size_t)N*2));
  float* x1CN = (float*)(ws + A((size_t)N*64*4));
  unsigned short* xh1 = (unsigned short*)(ws + A((size_t)N*64*2));
  unsigned short* xx1 = (unsigned short*)(ws + A((size_t)N*2));
  float* x2CN = (float*)(ws + A((size_t)N*64*4));
  unsigned short* xh2 = (unsigned short*)(ws + A((size_t)N*64*2));
  unsigned short* xx2 = (unsigned short*)(ws + A((size_t)N*2));
  float* x3CN = (float*)(ws + A((size_t)N*64*4));
  int* idxb = (int*)(ws + A((size_t)N*KNN_K*4));    // reused across rounds
  float* Ut  = (float*)(ws + A((size_t)N*64*4));    // reused across rounds
  float* Vtb = (float*)(ws + A((size_t)N*64*4));
  float* w6t  = (float*)(ws + A((size_t)192*1024*4));
  float* w7xt = (float*)(ws + A((size_t)192*512*4));
  float* w8t  = (float*)(ws + A((size_t)512*256*4));
  float* gpart= (float*)(ws + A((size_t)1024*NB*4));
  float* gbuf = (float*)(ws + A((size_t)1024*4));
  float* b7   = (float*)(ws + A((size_t)512*4));

  size_t h7B   = (size_t)512*N*4;
  size_t h8B   = (size_t)256*N*4;
  size_t uniOff = A(((h7B + 255) & ~(size_t)255) + h8B);
  float* h7   = (float*)(ws + uniOff);
  float* h8   = (float*)(ws + uniOff + ((h7B + 255) & ~(size_t)255));
  if (off > ws_size) return;

  dim3 b256(256), b512(512);
  build_x0<<<dim3((N+255)/256), b256, 0, stream>>>(curr_pos, node_t, x0CN, xh0, xx0, N);
  transpose_w<<<dim3((1024*192+255)/256), b256, 0, stream>>>(W6, w6t, 1024, 192, 192, 0);
  transpose_w<<<dim3((512*192+255)/256),  b256, 0, stream>>>(W7, w7xt, 512, 192, 1216, 1024);
  transpose_w<<<dim3((256*512+255)/256),  b256, 0, stream>>>(W8, w8t, 256, 512, 512, 0);

  dim3 gknn(N/16);
  dim3 guv(N/256, 2, 2);
  dim3 gec(N/8);
  dim3 gfin((N+255)/256);

  // round 1
  knn_mfma<32><<<gknn, b512, 0, stream>>>(xh0, xx0, idxb, N);
  uv_kernel<12><<<guv, b256, 0, stream>>>(x0CN, W1, bn1, Ut, Vtb, N);
  edge2<true><<<gec, b256, 0, stream>>>(Ut, Vtb, idxb, W2, bn2, x1CN, xh1, xx1, N);
  // round 2
  knn_mfma<64><<<gknn, b512, 0, stream>>>(xh1, xx1, idxb, N);
  uv_kernel<64><<<guv, b256, 0, stream>>>(x1CN, W3, bn3, Ut, Vtb, N);
  edge2<true><<<gec, b256, 0, stream>>>(Ut, Vtb, idxb, W4, bn4, x2CN, xh2, xx2, N);
  // round 3
  knn_mfma<64><<<gknn, b512, 0, stream>>>(xh2, xx2, idxb, N);
  uv_kernel<64><<<guv, b256, 0, stream>>>(x2CN, W5, bn5, Ut, Vtb, N);
  edge2<false><<<gec, b256, 0, stream>>>(Ut, Vtb, idxb, nullptr, nullptr, x3CN, nullptr, nullptr, N);
  // head
  conv_fused<true><<<dim3(NB, 16), b256, 0, stream>>>(w6t, 1024, x1CN, 64, x2CN, 64, x3CN, 64, bn6, nullptr, gpart, N);
  gmax_final<<<dim3(4), b256, 0, stream>>>(gpart, gbuf, 1024, NB);
  bias7_kernel<<<dim3(2), b256, 0, stream>>>(W7, gbuf, b7);
  conv_fused<false><<<dim3(NB, 8), b256, 0, stream>>>(w7xt, 512, x1CN, 64, x2CN, 64, x3CN, 64, bn7, b7, h7, N);
  conv_fused<false><<<dim3(NB, 4), b256, 0, stream>>>(w8t, 256, h7, 512, nullptr, 0, nullptr, 0, bn8, nullptr, h8, N);
  w9_kernel<<<gfin, b256, 0, stream>>>(W9, h8, out, N);
}

// Round 5
// 1324.946 us; speedup vs baseline: 3.0676x; 1.0085x over previous
//
#include <hip/hip_runtime.h>
#include <hip/hip_bf16.h>

#define KNN_K 20
typedef _Float16 f16;
typedef _Float16 half8 __attribute__((ext_vector_type(8)));
typedef float f32x4 __attribute__((ext_vector_type(4)));

__device__ __forceinline__ float lrelu(float x){ return x >= 0.f ? x : 0.2f*x; }
__device__ __forceinline__ f16 us2h(unsigned short u){ union{unsigned short u; f16 h;} x; x.u=u; return x.h; }
__device__ __forceinline__ unsigned short h2us(f16 h){ union{unsigned short u; f16 h;} x; x.h=h; return x.u; }

// u32 key: [31:16] order-mapped f16 distance (desc), [15:0] ~m (idx asc). Unique.
__device__ __forceinline__ unsigned pack_key16(f16 v, int m){
  unsigned u = h2us(v);
  unsigned s = (u & 0x8000u) ? ((~u) & 0xFFFFu) : (u | 0x8000u);
  return (s << 16) | ((~(unsigned)m) & 0xFFFFu);
}

__device__ __forceinline__ void insert32(unsigned* tk, unsigned key){
  if (key > tk[KNN_K-1]){
    #pragma unroll
    for (int j = KNN_K-1; j >= 1; --j){
      unsigned pv = tk[j-1];
      bool keep = tk[j] > key;
      bool ins  = pv   > key;
      tk[j] = keep ? tk[j] : (ins ? key : pv);
    }
    if (tk[0] < key) tk[0] = key;
  }
}

__device__ __forceinline__ void merge_sorted(unsigned* tk, const unsigned* src){
  #pragma unroll
  for (int j=0;j<KNN_K;++j){
    unsigned key = src[j];
    if (key <= tk[KNN_K-1]) break;
    insert32(tk, key);
  }
}

// ---------------- build x0: CN f32 + padded f16 NC + xx ----------------
__global__ __launch_bounds__(256) void build_x0(
    const float* __restrict__ pos, const int* __restrict__ nt,
    float* __restrict__ x0CN, unsigned short* __restrict__ xh0,
    unsigned short* __restrict__ xx0, int N)
{
  int n = blockIdx.x*256 + threadIdx.x;
  if (n >= N) return;
  float v[12];
  v[0]=pos[n*3+0]; v[1]=pos[n*3+1]; v[2]=pos[n*3+2];
  int t = nt[n];
  #pragma unroll
  for (int c=0;c<9;++c) v[3+c] = (t==c) ? 1.f : 0.f;
  float xa = 0.f;
  #pragma unroll
  for (int c=0;c<12;++c){
    x0CN[(size_t)c*N+n] = v[c];
    f16 h = (f16)v[c];
    float hf = (float)h;
    xh0[(size_t)n*32+c] = h2us(h);
    f16 pe = (f16)(hf*hf);       // elementwise xh*xh rounds to f16
    xa += (float)pe;             // f32 accumulation (jax upcast semantics)
  }
  #pragma unroll
  for (int c=12;c<32;++c) xh0[(size_t)n*32+c] = 0;
  xx0[n] = h2us((f16)xa);
}

// ---------------- weight transpose: dst[c*O+o] = src[o*stride+coff+c] ----------------
__global__ __launch_bounds__(256) void transpose_w(
    const float* __restrict__ src, float* __restrict__ dst, int O, int C, int stride, int coff)
{
  int i = blockIdx.x*256 + threadIdx.x;
  if (i >= O*C) return;
  int o = i / C, c = i % C;
  dst[(size_t)c*O + o] = src[(size_t)o*stride + coff + c];
}

// ---------------- fused MFMA kNN: grid (N/16, 2 m-halves), 512 thr ----------------
template<int C>
__global__ __launch_bounds__(512) void knn_mfma(
    const unsigned short* __restrict__ xh,  // [N][C] f16 bits
    const unsigned short* __restrict__ xx,  // [N]   f16 bits
    unsigned* __restrict__ pl,              // [2][N][20] partial sorted keys
    int N)
{
  __shared__ unsigned lists[32][16][KNN_K+1];  // 43008 B, 21-pad -> conflict-free
  int tid = threadIdx.x;
  int w = tid >> 6, lane = tid & 63;
  int g = lane >> 4, c = lane & 15;
  int n0 = blockIdx.x * 16;
  int ms = blockIdx.y;
  int htiles = (N >> 7);            // tiles of 64 in this half

  half8 bfrag[C/32];
  #pragma unroll
  for (int kc=0; kc<C/32; ++kc)
    bfrag[kc] = *reinterpret_cast<const half8*>(xh + (size_t)(n0 + c)*C + kc*32 + g*8);
  f16 qxx = us2h(xx[n0 + c]);

  unsigned tk[KNN_K];
  #pragma unroll
  for (int j=0;j<KNN_K;++j) tk[j] = 0u;

  for (int t = w; t < htiles; t += 8){
    int mbase = ms*(N>>1) + (t << 6);
    #pragma unroll
    for (int msub=0; msub<4; ++msub){
      int mrow = mbase + msub*16;
      f32x4 acc = {0.f,0.f,0.f,0.f};
      #pragma unroll
      for (int kc=0; kc<C/32; ++kc){
        half8 af = *reinterpret_cast<const half8*>(xh + (size_t)(mrow + c)*C + kc*32 + g*8);
        acc = __builtin_amdgcn_mfma_f32_16x16x32_f16(af, bfrag[kc], acc, 0, 0, 0);
      }
      #pragma unroll
      for (int j=0;j<4;++j){
        int m = mrow + g*4 + j;
        f16 dh = (f16)acc[j];          // einsum output rounds to f16
        f16 mi = dh * (f16)(-2.0f);    // inner = -2*dot
        f16 xm = us2h(xx[m]);
        f16 t1 = (-xm) - mi;           // (-xx[m] - inner)
        f16 pdh = t1 - qxx;            // ... - xx[n]
        insert32(tk, pack_key16(pdh, m));
      }
    }
  }

  {
    unsigned* dst = lists[w*4 + g][c];
    #pragma unroll
    for (int j=0;j<KNN_K;++j) dst[j] = tk[j];
  }
  __syncthreads();

  // stage 1: 128 threads merge 4 lists each (in-place, staged via regs)
  unsigned tk2[KNN_K];
  if (tid < 128){
    int n = tid >> 3, q = tid & 7;
    #pragma unroll
    for (int j=0;j<KNN_K;++j) tk2[j] = lists[q*4][n][j];
    for (int li=1; li<4; ++li) merge_sorted(tk2, lists[q*4 + li][n]);
  }
  __syncthreads();
  if (tid < 128){
    int n = tid >> 3, q = tid & 7;
    unsigned* dst = lists[q][n];
    #pragma unroll
    for (int j=0;j<KNN_K;++j) dst[j] = tk2[j];
  }
  __syncthreads();
  // stage 2: 32 threads merge 4 -> 8 lists become 2
  if (tid < 32){
    int n = tid >> 1, h = tid & 1;
    #pragma unroll
    for (int j=0;j<KNN_K;++j) tk2[j] = lists[h*4][n][j];
    for (int li=1; li<4; ++li) merge_sorted(tk2, lists[h*4 + li][n]);
  }
  __syncthreads();
  if (tid < 32){
    int n = tid >> 1, h = tid & 1;
    unsigned* dst = lists[h][n];
    #pragma unroll
    for (int j=0;j<KNN_K;++j) dst[j] = tk2[j];
  }
  __syncthreads();
  // stage 3: 16 threads merge 2 -> global partial (sorted desc)
  if (tid < 16){
    int n = tid;
    #pragma unroll
    for (int j=0;j<KNN_K;++j) tk2[j] = lists[0][n][j];
    merge_sorted(tk2, lists[1][n]);
    unsigned* dst = pl + ((size_t)ms*N + n0 + n)*KNN_K;
    #pragma unroll
    for (int j=0;j<KNN_K;++j) dst[j] = tk2[j];
  }
}

// merge the 2 m-half partials -> final idx
__global__ __launch_bounds__(256) void knn_final(
    const unsigned* __restrict__ pl, int* __restrict__ idx, int N)
{
  int n = blockIdx.x*256 + threadIdx.x;
  if (n >= N) return;
  unsigned tk[KNN_K];
  const unsigned* p0 = pl + (size_t)n*KNN_K;
  const unsigned* p1 = pl + ((size_t)N + n)*KNN_K;
  #pragma unroll
  for (int j=0;j<KNN_K;++j) tk[j] = p0[j];
  merge_sorted(tk, p1);
  #pragma unroll
  for (int j=0;j<KNN_K;++j)
    idx[(size_t)n*KNN_K + j] = (int)((~tk[j]) & 0xFFFFu);
}

// ---------------- per-point U/V precompute: Ut = t*(Wd X); Vtb = t*((Wc-Wd)X - m) + b ----------------
template<int CIN>
__global__ __launch_bounds__(256) void uv_kernel(
    const float* __restrict__ xCN, const float* __restrict__ W,  // [64][2*CIN]
    const float* __restrict__ bn,
    float* __restrict__ Ut, float* __restrict__ Vtb, int N)
{
  __shared__ float Ws[32][CIN];
  int tid = threadIdx.x;
  int mode = blockIdx.y;      // 0 = U (neighbor term), 1 = V (center term)
  int ob = blockIdx.z * 32;
  for (int i = tid; i < 32*CIN; i += 256){
    int oo = i / CIN, cc = i % CIN;
    float wd = W[(size_t)(ob+oo)*(2*CIN) + cc];
    float wc = W[(size_t)(ob+oo)*(2*CIN) + CIN + cc];
    Ws[oo][cc] = mode ? (wc - wd) : wd;
  }
  __syncthreads();
  int n = blockIdx.x*256 + tid;
  float x[CIN];
  #pragma unroll
  for (int c2=0;c2<CIN;++c2) x[c2] = xCN[(size_t)c2*N + n];
  float acc[32];
  #pragma unroll
  for (int oo=0;oo<32;++oo) acc[oo] = 0.f;
  #pragma unroll 4
  for (int c2=0;c2<CIN;++c2){
    float xv = x[c2];
    #pragma unroll
    for (int oo=0;oo<32;++oo) acc[oo] = fmaf(Ws[oo][c2], xv, acc[oo]);
  }
  float* dst = mode ? Vtb : Ut;
  #pragma unroll
  for (int oo=0;oo<32;++oo){
    int o = ob + oo;
    float t = bn[o] / sqrtf(bn[192+o] + 1e-5f);
    float val = mode ? fmaf(acc[oo] - bn[128+o], t, bn[64+o]) : acc[oo]*t;
    dst[(size_t)n*64 + o] = val;
  }
}

// ---------------- edge conv: e = lrelu(Ut[j]+Vtb[n]); opt f2 = lrelu(bn2(W2 e)); max over k ----------------
// W2-dot via LDS same-address broadcast (double-buffered e vector), exact f32 quad-accum.
template<bool SECOND>
__global__ __launch_bounds__(256) void edge2(
    const float* __restrict__ Ut, const float* __restrict__ Vtb,
    const int* __restrict__ idx,
    const float* __restrict__ W2, const float* __restrict__ bn2,
    float* __restrict__ outCN, unsigned short* __restrict__ outh,
    unsigned short* __restrict__ outxx, int N)
{
  __shared__ float eb[2][4][64];
  int w = threadIdx.x >> 6, o = threadIdx.x & 63;
  float w2r[64]; float t2=0.f,b2=0.f,m2=0.f;
  if (SECOND){
    #pragma unroll
    for (int c4=0;c4<16;++c4){
      float4 wv = *reinterpret_cast<const float4*>(W2 + (size_t)o*64 + c4*4);
      w2r[c4*4+0]=wv.x; w2r[c4*4+1]=wv.y; w2r[c4*4+2]=wv.z; w2r[c4*4+3]=wv.w;
    }
    t2 = bn2[o]/sqrtf(bn2[192+o]+1e-5f); b2 = bn2[64+o]; m2 = bn2[128+o];
  }
  #pragma unroll 1
  for (int q=0;q<2;++q){
    int n = blockIdx.x*8 + w*2 + q;
    float vo = Vtb[(size_t)n*64 + o];
    float best = -INFINITY;
    #pragma unroll 1
    for (int k=0;k<KNN_K;++k){
      int j = idx[(size_t)n*KNN_K + k];
      float e = lrelu(Ut[(size_t)j*64 + o] + vo);
      if (SECOND){
        eb[k&1][w][o] = e;
        __syncthreads();
        const float* ep = eb[k&1][w];
        float s0=0.f,s1=0.f,s2=0.f,s3=0.f;
        #pragma unroll
        for (int c4=0;c4<16;++c4){
          float4 ev = *reinterpret_cast<const float4*>(ep + c4*4);
          s0 = fmaf(w2r[c4*4+0], ev.x, s0);
          s1 = fmaf(w2r[c4*4+1], ev.y, s1);
          s2 = fmaf(w2r[c4*4+2], ev.z, s2);
          s3 = fmaf(w2r[c4*4+3], ev.w, s3);
        }
        float s = (s0+s1)+(s2+s3);
        float f = lrelu(fmaf(s - m2, t2, b2));
        best = fmaxf(best, f);
      } else {
        best = fmaxf(best, e);
      }
    }
    outCN[(size_t)o*N + n] = best;
    if (SECOND){
      f16 h = (f16)best; float hf = (float)h;
      outh[(size_t)n*64 + o] = h2us(h);
      float pe = (float)(f16)(hf*hf);
      float ssum = pe;
      #pragma unroll
      for (int s2s=32;s2s>=1;s2s>>=1) ssum += __shfl_xor(ssum, s2s, 64);
      if (o == 0) outxx[n] = h2us((f16)ssum);
    }
  }
}

// ---------------- fused 1x1-conv: n-tile 64 x o-tile 64, 16 accs/thread ----------------
template<bool DOMAX>
__global__ __launch_bounds__(256) void conv_fused(
    const float* __restrict__ WT, int O,
    const float* __restrict__ sA, int cAn,
    const float* __restrict__ sB, int cBn,
    const float* __restrict__ sC, int cCn,
    const float* __restrict__ bnp,
    const float* __restrict__ extra,
    float* __restrict__ out, int N)
{
  int tid = threadIdx.x;
  int ln = tid & 63;
  int og = (tid >> 6) * 16;         // wave-uniform
  int n = blockIdx.x*64 + ln;
  int ob = blockIdx.y*64;
  float acc[16];
  #pragma unroll
  for (int i=0;i<16;++i) acc[i] = 0.f;

  const float* srcs[3] = {sA, sB, sC};
  int cnts[3] = {cAn, cBn, cCn};
  int cbase = 0;
  #pragma unroll 1
  for (int sidx=0; sidx<3; ++sidx){
    const float* s = srcs[sidx];
    if (!s) continue;
    int cn = cnts[sidx];
    #pragma unroll 1
    for (int c=0;c<cn;++c){
      float xv = s[(size_t)c*N + n];
      const float* wr = WT + (size_t)(cbase+c)*O + ob + og;
      #pragma unroll
      for (int i=0;i<16;++i) acc[i] = fmaf(wr[i], xv, acc[i]);
    }
    cbase += cn;
  }
  #pragma unroll
  for (int i=0;i<16;++i){
    int oG = ob + og + i;
    float a = acc[i];
    if (extra) a += extra[oG];
    float t = bnp[oG] / sqrtf(bnp[3*O+oG] + 1e-5f);
    a = fmaf(a - bnp[2*O+oG], t, bnp[1*O+oG]);
    acc[i] = lrelu(a);
  }
  if (!DOMAX){
    #pragma unroll
    for (int i=0;i<16;++i) out[(size_t)(ob+og+i)*N + n] = acc[i];
  } else {
    #pragma unroll
    for (int i=0;i<16;++i){
      float v = acc[i];
      #pragma unroll
      for (int s=32;s>=1;s>>=1) v = fmaxf(v, __shfl_xor(v, s, 64));
      if (ln == 0) out[(size_t)(ob+og+i)*gridDim.x + blockIdx.x] = v;
    }
  }
}

__global__ __launch_bounds__(256) void gmax_final(
    const float* __restrict__ gpart, float* __restrict__ g, int O, int P)
{
  int o = blockIdx.x*256 + threadIdx.x;
  if (o >= O) return;
  float m = -INFINITY;
  for (int p=0;p<P;++p) m = fmaxf(m, gpart[(size_t)o*P + p]);
  g[o] = m;
}

__global__ __launch_bounds__(256) void bias7_kernel(
    const float* __restrict__ W7, const float* __restrict__ g, float* __restrict__ b7)
{
  int o = blockIdx.x*256 + threadIdx.x;
  if (o >= 512) return;
  float a = 0.f;
  for (int c=0;c<1024;++c) a = fmaf(W7[(size_t)o*1216 + c], g[c], a);
  b7[o] = a;
}

__global__ __launch_bounds__(256) void w9_kernel(
    const float* __restrict__ W9, const float* __restrict__ h8, float* __restrict__ out, int N)
{
  int n = blockIdx.x*256 + threadIdx.x;
  if (n >= N) return;
  float a0=0.f, a1=0.f, a2=0.f;
  for (int c=0;c<256;++c){
    float xv = h8[(size_t)c*N + n];
    a0 = fmaf(W9[c],       xv, a0);
    a1 = fmaf(W9[256+c],   xv, a1);
    a2 = fmaf(W9[512+c],   xv, a2);
  }
  out[(size_t)n*3+0]=a0; out[(size_t)n*3+1]=a1; out[(size_t)n*3+2]=a2;
}

extern "C" void kernel_launch(void* const* d_in, const int* in_sizes, int n_in,
                              void* d_out, int out_size, void* d_ws, size_t ws_size,
                              hipStream_t stream) {
  const float* curr_pos = (const float*)d_in[0];
  const int*   node_t   = (const int*)  d_in[1];
  const float* W1 = (const float*)d_in[2];
  const float* W2 = (const float*)d_in[3];
  const float* W3 = (const float*)d_in[4];
  const float* W4 = (const float*)d_in[5];
  const float* W5 = (const float*)d_in[6];
  const float* W6 = (const float*)d_in[7];
  const float* W7 = (const float*)d_in[8];
  const float* W8 = (const float*)d_in[9];
  const float* W9 = (const float*)d_in[10];
  const float* bn1 = (const float*)d_in[11];
  const float* bn2 = (const float*)d_in[12];
  const float* bn3 = (const float*)d_in[13];
  const float* bn4 = (const float*)d_in[14];
  const float* bn5 = (const float*)d_in[15];
  const float* bn6 = (const float*)d_in[16];
  const float* bn7 = (const float*)d_in[17];
  const float* bn8 = (const float*)d_in[18];
  float* out = (float*)d_out;

  const int N = in_sizes[0] / 3;

  char* ws = (char*)d_ws;
  size_t off = 0;
  auto A = [&](size_t b){ size_t o = off; off = (o + b + 255) & ~(size_t)255; return o; };

  float* x0CN = (float*)(ws + A((size_t)N*12*4));
  unsigned short* xh0 = (unsigned short*)(ws + A((size_t)N*32*2));
  unsigned short* xx0 = (unsigned short*)(ws + A((size_t)N*2));
  float* x1CN = (float*)(ws + A((size_t)N*64*4));
  unsigned short* xh1 = (unsigned short*)(ws + A((size_t)N*64*2));
  unsigned short* xx1 = (unsigned short*)(ws + A((size_t)N*2));
  float* x2CN = (float*)(ws + A((size_t)N*64*4));
  unsigned short* xh2 = (unsigned short*)(ws + A((size_t)N*64*2));
  unsigned short* xx2 = (unsigned short*)(ws + A((size_t)N*2));
  float* x3CN = (float*)(ws + A((size_t)N*64*4));
  int* idxb = (int*)(ws + A((size_t)N*KNN_K*4));
  unsigned* pl = (unsigned*)(ws + A((size_t)2*N*KNN_K*4));
  float* Ut  = (float*)(ws + A((size_t)N*64*4));
  float* Vtb = (float*)(ws + A((size_t)N*64*4));
  float* w6t  = (float*)(ws + A((size_t)192*1024*4));
  float* w7xt = (float*)(ws + A((size_t)192*512*4));
  float* w8t  = (float*)(ws + A((size_t)512*256*4));
  float* gpart= (float*)(ws + A((size_t)1024*(N/64)*4));
  float* gbuf = (float*)(ws + A((size_t)1024*4));
  float* b7   = (float*)(ws + A((size_t)512*4));

  size_t h7B   = (size_t)512*N*4;
  size_t h8B   = (size_t)256*N*4;
  size_t uniOff = A(((h7B + 255) & ~(size_t)255) + h8B);
  float* h7   = (float*)(ws + uniOff);
  float* h8   = (float*)(ws + uniOff + ((h7B + 255) & ~(size_t)255));
  if (off > ws_size) return;

  dim3 b256(256), b512(512);
  build_x0<<<dim3((N+255)/256), b256, 0, stream>>>(curr_pos, node_t, x0CN, xh0, xx0, N);
  transpose_w<<<dim3((1024*192+255)/256), b256, 0, stream>>>(W6, w6t, 1024, 192, 192, 0);
  transpose_w<<<dim3((512*192+255)/256),  b256, 0, stream>>>(W7, w7xt, 512, 192, 1216, 1024);
  transpose_w<<<dim3((256*512+255)/256),  b256, 0, stream>>>(W8, w8t, 256, 512, 512, 0);

  dim3 gknn(N/16, 2);
  dim3 guv(N/256, 2, 2);
  dim3 gec(N/8);
  dim3 gfin((N+255)/256);

  // round 1
  knn_mfma<32><<<gknn, b512, 0, stream>>>(xh0, xx0, pl, N);
  knn_final<<<gfin, b256, 0, stream>>>(pl, idxb, N);
  uv_kernel<12><<<guv, b256, 0, stream>>>(x0CN, W1, bn1, Ut, Vtb, N);
  edge2<true><<<gec, b256, 0, stream>>>(Ut, Vtb, idxb, W2, bn2, x1CN, xh1, xx1, N);
  // round 2
  knn_mfma<64><<<gknn, b512, 0, stream>>>(xh1, xx1, pl, N);
  knn_final<<<gfin, b256, 0, stream>>>(pl, idxb, N);
  uv_kernel<64><<<guv, b256, 0, stream>>>(x1CN, W3, bn3, Ut, Vtb, N);
  edge2<true><<<gec, b256, 0, stream>>>(Ut, Vtb, idxb, W4, bn4, x2CN, xh2, xx2, N);
  // round 3
  knn_mfma<64><<<gknn, b512, 0, stream>>>(xh2, xx2, pl, N);
  knn_final<<<gfin, b256, 0, stream>>>(pl, idxb, N);
  uv_kernel<64><<<guv, b256, 0, stream>>>(x2CN, W5, bn5, Ut, Vtb, N);
  edge2<false><<<gec, b256, 0, stream>>>(Ut, Vtb, idxb, nullptr, nullptr, x3CN, nullptr, nullptr, N);
  // head
  conv_fused<true><<<dim3(N/64, 16), b256, 0, stream>>>(w6t, 1024, x1CN, 64, x2CN, 64, x3CN, 64, bn6, nullptr, gpart, N);
  gmax_final<<<dim3(4), b256, 0, stream>>>(gpart, gbuf, 1024, N/64);
  bias7_kernel<<<dim3(2), b256, 0, stream>>>(W7, gbuf, b7);
  conv_fused<false><<<dim3(N/64, 8), b256, 0, stream>>>(w7xt, 512, x1CN, 64, x2CN, 64, x3CN, 64, bn7, b7, h7, N);
  conv_fused<false><<<dim3(N/64, 4), b256, 0, stream>>>(w8t, 256, h7, 512, nullptr, 0, nullptr, 0, bn8, nullptr, h8, N);
  w9_kernel<<<gfin, b256, 0, stream>>>(W9, h8, out, N);
}

// Round 6
// 1070.296 us; speedup vs baseline: 3.7975x; 1.2379x over previous
//
#include <hip/hip_runtime.h>
#include <hip/hip_bf16.h>

#define KNN_K 20
typedef _Float16 f16;
typedef _Float16 half8 __attribute__((ext_vector_type(8)));
typedef float f32x4 __attribute__((ext_vector_type(4)));

__device__ __forceinline__ float lrelu(float x){ return x >= 0.f ? x : 0.2f*x; }
__device__ __forceinline__ f16 us2h(unsigned short u){ union{unsigned short u; f16 h;} x; x.u=u; return x.h; }
__device__ __forceinline__ unsigned short h2us(f16 h){ union{unsigned short u; f16 h;} x; x.h=h; return x.u; }

// u32 key: [31:16] order-mapped f16 distance (desc), [15:0] ~m (idx asc). Unique.
__device__ __forceinline__ unsigned pack_key16(f16 v, int m){
  unsigned u = h2us(v);
  unsigned s = (u & 0x8000u) ? ((~u) & 0xFFFFu) : (u | 0x8000u);
  return (s << 16) | ((~(unsigned)m) & 0xFFFFu);
}

__device__ __forceinline__ void insert32(unsigned* tk, unsigned key){
  if (key > tk[KNN_K-1]){
    #pragma unroll
    for (int j = KNN_K-1; j >= 1; --j){
      unsigned pv = tk[j-1];
      bool keep = tk[j] > key;
      bool ins  = pv   > key;
      tk[j] = keep ? tk[j] : (ins ? key : pv);
    }
    if (tk[0] < key) tk[0] = key;
  }
}

__device__ __forceinline__ void merge_sorted(unsigned* tk, const unsigned* src){
  #pragma unroll
  for (int j=0;j<KNN_K;++j){
    unsigned key = src[j];
    if (key <= tk[KNN_K-1]) break;
    insert32(tk, key);
  }
}

// ---------------- build x0: CN f32 + padded f16 NC + xx ----------------
__global__ __launch_bounds__(256) void build_x0(
    const float* __restrict__ pos, const int* __restrict__ nt,
    float* __restrict__ x0CN, unsigned short* __restrict__ xh0,
    unsigned short* __restrict__ xx0, int N)
{
  int n = blockIdx.x*256 + threadIdx.x;
  if (n >= N) return;
  float v[12];
  v[0]=pos[n*3+0]; v[1]=pos[n*3+1]; v[2]=pos[n*3+2];
  int t = nt[n];
  #pragma unroll
  for (int c=0;c<9;++c) v[3+c] = (t==c) ? 1.f : 0.f;
  float xa = 0.f;
  #pragma unroll
  for (int c=0;c<12;++c){
    x0CN[(size_t)c*N+n] = v[c];
    f16 h = (f16)v[c];
    float hf = (float)h;
    xh0[(size_t)n*32+c] = h2us(h);
    f16 pe = (f16)(hf*hf);       // elementwise xh*xh rounds to f16
    xa += (float)pe;             // f32 accumulation (jax upcast semantics)
  }
  #pragma unroll
  for (int c=12;c<32;++c) xh0[(size_t)n*32+c] = 0;
  xx0[n] = h2us((f16)xa);
}

// ---------------- weight transpose: dst[c*O+o] = src[o*stride+coff+c] ----------------
__global__ __launch_bounds__(256) void transpose_w(
    const float* __restrict__ src, float* __restrict__ dst, int O, int C, int stride, int coff)
{
  int i = blockIdx.x*256 + threadIdx.x;
  if (i >= O*C) return;
  int o = i / C, c = i % C;
  dst[(size_t)c*O + o] = src[(size_t)o*stride + coff + c];
}

// ---------------- fused MFMA kNN: grid (N/16, 2 m-halves), 512 thr ----------------
template<int C>
__global__ __launch_bounds__(512) void knn_mfma(
    const unsigned short* __restrict__ xh,  // [N][C] f16 bits
    const unsigned short* __restrict__ xx,  // [N]   f16 bits
    unsigned* __restrict__ pl,              // [2][N][20] partial sorted keys
    int N)
{
  __shared__ unsigned lists[32][16][KNN_K+1];  // 43008 B, 21-pad -> conflict-free
  int tid = threadIdx.x;
  int w = tid >> 6, lane = tid & 63;
  int g = lane >> 4, c = lane & 15;
  int n0 = blockIdx.x * 16;
  int ms = blockIdx.y;
  int htiles = (N >> 7);            // tiles of 64 in this half

  half8 bfrag[C/32];
  #pragma unroll
  for (int kc=0; kc<C/32; ++kc)
    bfrag[kc] = *reinterpret_cast<const half8*>(xh + (size_t)(n0 + c)*C + kc*32 + g*8);
  f16 qxx = us2h(xx[n0 + c]);

  unsigned tk[KNN_K];
  #pragma unroll
  for (int j=0;j<KNN_K;++j) tk[j] = 0u;

  for (int t = w; t < htiles; t += 8){
    int mbase = ms*(N>>1) + (t << 6);
    #pragma unroll
    for (int msub=0; msub<4; ++msub){
      int mrow = mbase + msub*16;
      f32x4 acc = {0.f,0.f,0.f,0.f};
      #pragma unroll
      for (int kc=0; kc<C/32; ++kc){
        half8 af = *reinterpret_cast<const half8*>(xh + (size_t)(mrow + c)*C + kc*32 + g*8);
        acc = __builtin_amdgcn_mfma_f32_16x16x32_f16(af, bfrag[kc], acc, 0, 0, 0);
      }
      #pragma unroll
      for (int j=0;j<4;++j){
        int m = mrow + g*4 + j;
        f16 dh = (f16)acc[j];          // einsum output rounds to f16
        f16 mi = dh * (f16)(-2.0f);    // inner = -2*dot
        f16 xm = us2h(xx[m]);
        f16 t1 = (-xm) - mi;           // (-xx[m] - inner)
        f16 pdh = t1 - qxx;            // ... - xx[n]
        insert32(tk, pack_key16(pdh, m));
      }
    }
  }

  {
    unsigned* dst = lists[w*4 + g][c];
    #pragma unroll
    for (int j=0;j<KNN_K;++j) dst[j] = tk[j];
  }
  __syncthreads();

  unsigned tk2[KNN_K];
  if (tid < 128){
    int n = tid >> 3, q = tid & 7;
    #pragma unroll
    for (int j=0;j<KNN_K;++j) tk2[j] = lists[q*4][n][j];
    for (int li=1; li<4; ++li) merge_sorted(tk2, lists[q*4 + li][n]);
  }
  __syncthreads();
  if (tid < 128){
    int n = tid >> 3, q = tid & 7;
    unsigned* dst = lists[q][n];
    #pragma unroll
    for (int j=0;j<KNN_K;++j) dst[j] = tk2[j];
  }
  __syncthreads();
  if (tid < 32){
    int n = tid >> 1, h = tid & 1;
    #pragma unroll
    for (int j=0;j<KNN_K;++j) tk2[j] = lists[h*4][n][j];
    for (int li=1; li<4; ++li) merge_sorted(tk2, lists[h*4 + li][n]);
  }
  __syncthreads();
  if (tid < 32){
    int n = tid >> 1, h = tid & 1;
    unsigned* dst = lists[h][n];
    #pragma unroll
    for (int j=0;j<KNN_K;++j) dst[j] = tk2[j];
  }
  __syncthreads();
  if (tid < 16){
    int n = tid;
    #pragma unroll
    for (int j=0;j<KNN_K;++j) tk2[j] = lists[0][n][j];
    merge_sorted(tk2, lists[1][n]);
    unsigned* dst = pl + ((size_t)ms*N + n0 + n)*KNN_K;
    #pragma unroll
    for (int j=0;j<KNN_K;++j) dst[j] = tk2[j];
  }
}

// merge the 2 m-half partials -> final idx
__global__ __launch_bounds__(256) void knn_final(
    const unsigned* __restrict__ pl, int* __restrict__ idx, int N)
{
  int n = blockIdx.x*256 + threadIdx.x;
  if (n >= N) return;
  unsigned tk[KNN_K];
  const unsigned* p0 = pl + (size_t)n*KNN_K;
  const unsigned* p1 = pl + ((size_t)N + n)*KNN_K;
  #pragma unroll
  for (int j=0;j<KNN_K;++j) tk[j] = p0[j];
  merge_sorted(tk, p1);
  #pragma unroll
  for (int j=0;j<KNN_K;++j)
    idx[(size_t)n*KNN_K + j] = (int)((~tk[j]) & 0xFFFFu);
}

// ---------------- per-point U/V precompute: Ut = t*(Wd X); Vtb = t*((Wc-Wd)X - m) + b ----------------
template<int CIN>
__global__ __launch_bounds__(256) void uv_kernel(
    const float* __restrict__ xCN, const float* __restrict__ W,  // [64][2*CIN]
    const float* __restrict__ bn,
    float* __restrict__ Ut, float* __restrict__ Vtb, int N)
{
  __shared__ float Ws[32][CIN];
  int tid = threadIdx.x;
  int mode = blockIdx.y;      // 0 = U (neighbor term), 1 = V (center term)
  int ob = blockIdx.z * 32;
  for (int i = tid; i < 32*CIN; i += 256){
    int oo = i / CIN, cc = i % CIN;
    float wd = W[(size_t)(ob+oo)*(2*CIN) + cc];
    float wc = W[(size_t)(ob+oo)*(2*CIN) + CIN + cc];
    Ws[oo][cc] = mode ? (wc - wd) : wd;
  }
  __syncthreads();
  int n = blockIdx.x*256 + tid;
  float x[CIN];
  #pragma unroll
  for (int c2=0;c2<CIN;++c2) x[c2] = xCN[(size_t)c2*N + n];
  float acc[32];
  #pragma unroll
  for (int oo=0;oo<32;++oo) acc[oo] = 0.f;
  #pragma unroll 4
  for (int c2=0;c2<CIN;++c2){
    float xv = x[c2];
    #pragma unroll
    for (int oo=0;oo<32;++oo) acc[oo] = fmaf(Ws[oo][c2], xv, acc[oo]);
  }
  float* dst = mode ? Vtb : Ut;
  #pragma unroll
  for (int oo=0;oo<32;++oo){
    int o = ob + oo;
    float t = bn[o] / sqrtf(bn[192+o] + 1e-5f);
    float val = mode ? fmaf(acc[oo] - bn[128+o], t, bn[64+o]) : acc[oo]*t;
    dst[(size_t)n*64 + o] = val;
  }
}

// ---------------- edge conv: e = lrelu(Ut[j]+Vtb[n]); opt f2 = lrelu(bn2(W2 e)); max over k ----------------
template<bool SECOND>
__global__ __launch_bounds__(256) void edge2(
    const float* __restrict__ Ut, const float* __restrict__ Vtb,
    const int* __restrict__ idx,
    const float* __restrict__ W2, const float* __restrict__ bn2,
    float* __restrict__ outCN, unsigned short* __restrict__ outh,
    unsigned short* __restrict__ outxx, int N)
{
  __shared__ float eb[2][4][64];
  int w = threadIdx.x >> 6, o = threadIdx.x & 63;
  float w2r[64]; float t2=0.f,b2=0.f,m2=0.f;
  if (SECOND){
    #pragma unroll
    for (int c4=0;c4<16;++c4){
      float4 wv = *reinterpret_cast<const float4*>(W2 + (size_t)o*64 + c4*4);
      w2r[c4*4+0]=wv.x; w2r[c4*4+1]=wv.y; w2r[c4*4+2]=wv.z; w2r[c4*4+3]=wv.w;
    }
    t2 = bn2[o]/sqrtf(bn2[192+o]+1e-5f); b2 = bn2[64+o]; m2 = bn2[128+o];
  }
  #pragma unroll 1
  for (int q=0;q<2;++q){
    int n = blockIdx.x*8 + w*2 + q;
    float vo = Vtb[(size_t)n*64 + o];
    float best = -INFINITY;
    #pragma unroll 1
    for (int k=0;k<KNN_K;++k){
      int j = idx[(size_t)n*KNN_K + k];
      float e = lrelu(Ut[(size_t)j*64 + o] + vo);
      if (SECOND){
        eb[k&1][w][o] = e;
        __syncthreads();
        const float* ep = eb[k&1][w];
        float s0=0.f,s1=0.f,s2=0.f,s3=0.f;
        #pragma unroll
        for (int c4=0;c4<16;++c4){
          float4 ev = *reinterpret_cast<const float4*>(ep + c4*4);
          s0 = fmaf(w2r[c4*4+0], ev.x, s0);
          s1 = fmaf(w2r[c4*4+1], ev.y, s1);
          s2 = fmaf(w2r[c4*4+2], ev.z, s2);
          s3 = fmaf(w2r[c4*4+3], ev.w, s3);
        }
        float s = (s0+s1)+(s2+s3);
        float f = lrelu(fmaf(s - m2, t2, b2));
        best = fmaxf(best, f);
      } else {
        best = fmaxf(best, e);
      }
    }
    outCN[(size_t)o*N + n] = best;
    if (SECOND){
      f16 h = (f16)best; float hf = (float)h;
      outh[(size_t)n*64 + o] = h2us(h);
      float pe = (float)(f16)(hf*hf);
      float ssum = pe;
      #pragma unroll
      for (int s2s=32;s2s>=1;s2s>>=1) ssum += __shfl_xor(ssum, s2s, 64);
      if (o == 0) outxx[n] = h2us((f16)ssum);
    }
  }
}

// ---------------- fused 1x1-conv v3: o-tile 64 x n-tile 128, LDS-staged weights ----------------
// Each thread: 16 o x 2 n. Weights staged per 32-c chunk (conflict-free, wave-uniform reads).
// f32 accumulation in the SAME linear c-order as before (bit-identical results).
template<bool DOMAX>
__global__ __launch_bounds__(256) void conv_fused(
    const float* __restrict__ WT, int O,
    const float* __restrict__ sA, int cAn,
    const float* __restrict__ sB, int cBn,
    const float* __restrict__ sC, int cCn,
    const float* __restrict__ bnp,
    const float* __restrict__ extra,
    float* __restrict__ out, int N)
{
  __shared__ float ws[32][68];
  int tid = threadIdx.x;
  int ln = tid & 63;
  int og = (tid >> 6) * 16;          // wave-uniform o sub-offset
  int n0 = blockIdx.x*128;
  int ob = blockIdx.y*64;
  int n = n0 + ln*2;
  float a0[16], a1[16];
  #pragma unroll
  for (int i=0;i<16;++i){ a0[i]=0.f; a1[i]=0.f; }

  const float* srcs[3] = {sA, sB, sC};
  int cnts[3] = {cAn, cBn, cCn};
  int cbase = 0;
  #pragma unroll 1
  for (int sidx=0; sidx<3; ++sidx){
    const float* s = srcs[sidx];
    if (!s) continue;
    int cn = cnts[sidx];
    #pragma unroll 1
    for (int c0=0; c0<cn; c0+=32){
      __syncthreads();
      // stage 32x64 weight tile: i over 2048 elems, coalesced
      #pragma unroll
      for (int r=0;r<8;++r){
        int i = r*256 + tid;
        int cc = i >> 6, oo = i & 63;
        ws[cc][oo] = WT[(size_t)(cbase+c0+cc)*O + ob + oo];
      }
      __syncthreads();
      #pragma unroll 4
      for (int cc=0; cc<32; ++cc){
        float2 xv = *reinterpret_cast<const float2*>(s + (size_t)(c0+cc)*N + n);
        const float* wr = &ws[cc][og];
        #pragma unroll
        for (int i=0;i<16;++i){
          a0[i] = fmaf(wr[i], xv.x, a0[i]);
          a1[i] = fmaf(wr[i], xv.y, a1[i]);
        }
      }
    }
    cbase += cn;
  }
  #pragma unroll
  for (int i=0;i<16;++i){
    int oG = ob + og + i;
    float t = bnp[oG] / sqrtf(bnp[3*O+oG] + 1e-5f);
    float e = extra ? extra[oG] : 0.f;
    float mm = bnp[2*O+oG], bb = bnp[1*O+oG];
    a0[i] = lrelu(fmaf((a0[i]+e) - mm, t, bb));
    a1[i] = lrelu(fmaf((a1[i]+e) - mm, t, bb));
  }
  if (!DOMAX){
    #pragma unroll
    for (int i=0;i<16;++i){
      float2 st = {a0[i], a1[i]};
      *reinterpret_cast<float2*>(out + (size_t)(ob+og+i)*N + n) = st;
    }
  } else {
    #pragma unroll
    for (int i=0;i<16;++i){
      float v = fmaxf(a0[i], a1[i]);
      #pragma unroll
      for (int s=32;s>=1;s>>=1) v = fmaxf(v, __shfl_xor(v, s, 64));
      if (ln == 0) out[(size_t)(ob+og+i)*gridDim.x + blockIdx.x] = v;
    }
  }
}

__global__ __launch_bounds__(256) void gmax_final(
    const float* __restrict__ gpart, float* __restrict__ g, int O, int P)
{
  int o = blockIdx.x*256 + threadIdx.x;
  if (o >= O) return;
  float m = -INFINITY;
  for (int p=0;p<P;++p) m = fmaxf(m, gpart[(size_t)o*P + p]);
  g[o] = m;
}

// lane-parallel over c with shuffle reduce; one o per wave
__global__ __launch_bounds__(256) void bias7_kernel(
    const float* __restrict__ W7, const float* __restrict__ g, float* __restrict__ b7)
{
  int w = threadIdx.x >> 6, ln = threadIdx.x & 63;
  int o = blockIdx.x*4 + w;
  if (o >= 512) return;
  float a = 0.f;
  #pragma unroll
  for (int c0=0; c0<1024; c0+=64)
    a = fmaf(W7[(size_t)o*1216 + c0 + ln], g[c0 + ln], a);
  #pragma unroll
  for (int s=32;s>=1;s>>=1) a += __shfl_xor(a, s, 64);
  if (ln == 0) b7[o] = a;
}

__global__ __launch_bounds__(256) void w9_kernel(
    const float* __restrict__ W9, const float* __restrict__ h8, float* __restrict__ out, int N)
{
  int n = blockIdx.x*256 + threadIdx.x;
  if (n >= N) return;
  float a0=0.f, a1=0.f, a2=0.f;
  for (int c=0;c<256;++c){
    float xv = h8[(size_t)c*N + n];
    a0 = fmaf(W9[c],       xv, a0);
    a1 = fmaf(W9[256+c],   xv, a1);
    a2 = fmaf(W9[512+c],   xv, a2);
  }
  out[(size_t)n*3+0]=a0; out[(size_t)n*3+1]=a1; out[(size_t)n*3+2]=a2;
}

extern "C" void kernel_launch(void* const* d_in, const int* in_sizes, int n_in,
                              void* d_out, int out_size, void* d_ws, size_t ws_size,
                              hipStream_t stream) {
  const float* curr_pos = (const float*)d_in[0];
  const int*   node_t   = (const int*)  d_in[1];
  const float* W1 = (const float*)d_in[2];
  const float* W2 = (const float*)d_in[3];
  const float* W3 = (const float*)d_in[4];
  const float* W4 = (const float*)d_in[5];
  const float* W5 = (const float*)d_in[6];
  const float* W6 = (const float*)d_in[7];
  const float* W7 = (const float*)d_in[8];
  const float* W8 = (const float*)d_in[9];
  const float* W9 = (const float*)d_in[10];
  const float* bn1 = (const float*)d_in[11];
  const float* bn2 = (const float*)d_in[12];
  const float* bn3 = (const float*)d_in[13];
  const float* bn4 = (const float*)d_in[14];
  const float* bn5 = (const float*)d_in[15];
  const float* bn6 = (const float*)d_in[16];
  const float* bn7 = (const float*)d_in[17];
  const float* bn8 = (const float*)d_in[18];
  float* out = (float*)d_out;

  const int N = in_sizes[0] / 3;

  char* ws = (char*)d_ws;
  size_t off = 0;
  auto A = [&](size_t b){ size_t o = off; off = (o + b + 255) & ~(size_t)255; return o; };

  float* x0CN = (float*)(ws + A((size_t)N*12*4));
  unsigned short* xh0 = (unsigned short*)(ws + A((size_t)N*32*2));
  unsigned short* xx0 = (unsigned short*)(ws + A((size_t)N*2));
  float* x1CN = (float*)(ws + A((size_t)N*64*4));
  unsigned short* xh1 = (unsigned short*)(ws + A((size_t)N*64*2));
  unsigned short* xx1 = (unsigned short*)(ws + A((size_t)N*2));
  float* x2CN = (float*)(ws + A((size_t)N*64*4));
  unsigned short* xh2 = (unsigned short*)(ws + A((size_t)N*64*2));
  unsigned short* xx2 = (unsigned short*)(ws + A((size_t)N*2));
  float* x3CN = (float*)(ws + A((size_t)N*64*4));
  int* idxb = (int*)(ws + A((size_t)N*KNN_K*4));
  unsigned* pl = (unsigned*)(ws + A((size_t)2*N*KNN_K*4));
  float* Ut  = (float*)(ws + A((size_t)N*64*4));
  float* Vtb = (float*)(ws + A((size_t)N*64*4));
  float* w6t  = (float*)(ws + A((size_t)192*1024*4));
  float* w7xt = (float*)(ws + A((size_t)192*512*4));
  float* w8t  = (float*)(ws + A((size_t)512*256*4));
  float* gpart= (float*)(ws + A((size_t)1024*(N/64)*4));
  float* gbuf = (float*)(ws + A((size_t)1024*4));
  float* b7   = (float*)(ws + A((size_t)512*4));

  size_t h7B   = (size_t)512*N*4;
  size_t h8B   = (size_t)256*N*4;
  size_t uniOff = A(((h7B + 255) & ~(size_t)255) + h8B);
  float* h7   = (float*)(ws + uniOff);
  float* h8   = (float*)(ws + uniOff + ((h7B + 255) & ~(size_t)255));
  if (off > ws_size) return;

  dim3 b256(256), b512(512);
  build_x0<<<dim3((N+255)/256), b256, 0, stream>>>(curr_pos, node_t, x0CN, xh0, xx0, N);
  transpose_w<<<dim3((1024*192+255)/256), b256, 0, stream>>>(W6, w6t, 1024, 192, 192, 0);
  transpose_w<<<dim3((512*192+255)/256),  b256, 0, stream>>>(W7, w7xt, 512, 192, 1216, 1024);
  transpose_w<<<dim3((256*512+255)/256),  b256, 0, stream>>>(W8, w8t, 256, 512, 512, 0);

  dim3 gknn(N/16, 2);
  dim3 guv(N/256, 2, 2);
  dim3 gec(N/8);
  dim3 gfin((N+255)/256);

  // round 1
  knn_mfma<32><<<gknn, b512, 0, stream>>>(xh0, xx0, pl, N);
  knn_final<<<gfin, b256, 0, stream>>>(pl, idxb, N);
  uv_kernel<12><<<guv, b256, 0, stream>>>(x0CN, W1, bn1, Ut, Vtb, N);
  edge2<true><<<gec, b256, 0, stream>>>(Ut, Vtb, idxb, W2, bn2, x1CN, xh1, xx1, N);
  // round 2
  knn_mfma<64><<<gknn, b512, 0, stream>>>(xh1, xx1, pl, N);
  knn_final<<<gfin, b256, 0, stream>>>(pl, idxb, N);
  uv_kernel<64><<<guv, b256, 0, stream>>>(x1CN, W3, bn3, Ut, Vtb, N);
  edge2<true><<<gec, b256, 0, stream>>>(Ut, Vtb, idxb, W4, bn4, x2CN, xh2, xx2, N);
  // round 3
  knn_mfma<64><<<gknn, b512, 0, stream>>>(xh2, xx2, pl, N);
  knn_final<<<gfin, b256, 0, stream>>>(pl, idxb, N);
  uv_kernel<64><<<guv, b256, 0, stream>>>(x2CN, W5, bn5, Ut, Vtb, N);
  edge2<false><<<gec, b256, 0, stream>>>(Ut, Vtb, idxb, nullptr, nullptr, x3CN, nullptr, nullptr, N);
  // head
  conv_fused<true><<<dim3(N/128, 16), b256, 0, stream>>>(w6t, 1024, x1CN, 64, x2CN, 64, x3CN, 64, bn6, nullptr, gpart, N);
  gmax_final<<<dim3(4), b256, 0, stream>>>(gpart, gbuf, 1024, N/128);
  bias7_kernel<<<dim3(128), b256, 0, stream>>>(W7, gbuf, b7);
  conv_fused<false><<<dim3(N/128, 8), b256, 0, stream>>>(w7xt, 512, x1CN, 64, x2CN, 64, x3CN, 64, bn7, b7, h7, N);
  conv_fused<false><<<dim3(N/128, 4), b256, 0, stream>>>(w8t, 256, h7, 512, nullptr, 0, nullptr, 0, bn8, nullptr, h8, N);
  w9_kernel<<<gfin, b256, 0, stream>>>(W9, h8, out, N);
}